// Round 5
// baseline (748.844 us; speedup 1.0000x reference)
//
#include <hip/hip_runtime.h>

// RGATNetwork: 2x RGATConv (R=4, H=4, C=32, HC=128, F_E=16) on N=50k nodes, E=800k edges.
// R5: proj moved to matrix cores via split-bf16 (3-term MFMA decomposition):
//   x = xhi+xlo, w = whi+wlo (bf16 RNE), x@w ~= xhi@whi + xhi@wlo + xlo@whi.
//   proj_mfma reads fragments directly from global (w L2-hot, x L3-resident):
//   NO LDS, NO barriers in the K-loop. 16x16x32 bf16 MFMA, verified layouts:
//   A[m=lane&15][k=quad*8+j], B[k=quad*8+j][n=lane&15], D col=lane&15 row=quad*4+reg.
// Rest unchanged from R4 (CSR gather agg, hierarchical scan).

#define NEG_SLOPE 0.2f
#define SOFT_EPS 1e-16f

typedef __attribute__((ext_vector_type(8))) short bf16x8;
typedef __attribute__((ext_vector_type(4))) float f32x4;

__device__ __forceinline__ void bf16split(float f, unsigned short& h, unsigned short& l) {
  unsigned u = __float_as_uint(f);
  unsigned r = u + 0x7FFFu + ((u >> 16) & 1u);
  h = (unsigned short)(r >> 16);
  float fh = __uint_as_float(((unsigned)h) << 16);
  float d = f - fh;
  unsigned u2 = __float_as_uint(d);
  unsigned r2 = u2 + 0x7FFFu + ((u2 >> 16) & 1u);
  l = (unsigned short)(r2 >> 16);
}

// lee[f,h] = sum_o le[f,o]*e[o,h]  for both layers (t<64: layer1, t>=64: layer3)
__global__ void lee_kernel(const float* __restrict__ le1, const float* __restrict__ e1,
                           const float* __restrict__ le3, const float* __restrict__ e3,
                           float* __restrict__ lee) {
  int t = threadIdx.x;
  const float* le = (t < 64) ? le1 : le3;
  const float* ee = (t < 64) ? e1 : e3;
  int u = t & 63, f = u >> 2, h = u & 3;
  float acc = 0.f;
  for (int o = 0; o < 128; ++o) acc += le[f * 128 + o] * ee[o * 4 + h];
  lee[t] = acc;
}

// ---- CSR build ----
__global__ __launch_bounds__(256) void hist_kernel(const int* __restrict__ dst,
                                                   int* __restrict__ deg, int E) {
  int e = blockIdx.x * 256 + threadIdx.x;
  if (e < E) atomicAdd(&deg[dst[e]], 1);
}

__global__ __launch_bounds__(256) void scanA_kernel(const int* __restrict__ deg,
                                                    int* __restrict__ bsum, int N) {
  int b = blockIdx.x, t = threadIdx.x;
  int base = b * 1024 + t * 4;
  int s = 0;
#pragma unroll
  for (int j = 0; j < 4; ++j) {
    int i = base + j;
    if (i < N) s += deg[i];
  }
#pragma unroll
  for (int o = 1; o < 64; o <<= 1) s += __shfl_xor(s, o);
  __shared__ int wsum[4];
  if ((t & 63) == 0) wsum[t >> 6] = s;
  __syncthreads();
  if (t == 0) bsum[b] = wsum[0] + wsum[1] + wsum[2] + wsum[3];
}

__global__ __launch_bounds__(256) void scanB_kernel(const int* __restrict__ bsum,
                                                    int* __restrict__ boff,
                                                    int* __restrict__ row_start,
                                                    int nb, int N) {
  int t = threadIdx.x;
  int v = (t < nb) ? bsum[t] : 0;
  int inc = v;
#pragma unroll
  for (int o = 1; o < 64; o <<= 1) {
    int u = __shfl_up(inc, o);
    if ((t & 63) >= o) inc += u;
  }
  __shared__ int wt[4];
  if ((t & 63) == 63) wt[t >> 6] = inc;
  __syncthreads();
  int add = 0;
  for (int wv = 0; wv < (t >> 6); ++wv) add += wt[wv];
  inc += add;
  if (t < nb) boff[t] = inc - v;
  if (t == 255) row_start[N] = inc;
}

__global__ __launch_bounds__(256) void scanC_kernel(const int* __restrict__ deg,
                                                    const int* __restrict__ boff,
                                                    int* __restrict__ row_start,
                                                    int* __restrict__ cursor, int N) {
  int b = blockIdx.x, t = threadIdx.x;
  int base = b * 1024 + t * 4;
  int d[4];
  int s = 0;
#pragma unroll
  for (int j = 0; j < 4; ++j) {
    int i = base + j;
    d[j] = (i < N) ? deg[i] : 0;
    s += d[j];
  }
  int inc = s;
#pragma unroll
  for (int o = 1; o < 64; o <<= 1) {
    int u = __shfl_up(inc, o);
    if ((t & 63) >= o) inc += u;
  }
  __shared__ int wt[4];
  if ((t & 63) == 63) wt[t >> 6] = inc;
  __syncthreads();
  int add = boff[b];
  for (int wv = 0; wv < (t >> 6); ++wv) add += wt[wv];
  int off = add + inc - s;
#pragma unroll
  for (int j = 0; j < 4; ++j) {
    int i = base + j;
    if (i < N) {
      row_start[i] = off;
      cursor[i] = off;
      off += d[j];
    }
  }
}

__global__ __launch_bounds__(256) void scatter_kernel(
    const int* __restrict__ src, const int* __restrict__ dst, const int* __restrict__ et,
    int* __restrict__ cursor, int* __restrict__ es_src, int* __restrict__ es_dst,
    int* __restrict__ es_et, int* __restrict__ es_eid, int E) {
  int e = blockIdx.x * 256 + threadIdx.x;
  if (e >= E) return;
  int d = dst[e];
  int pos = atomicAdd(&cursor[d], 1);
  es_src[pos] = src[e];
  es_dst[pos] = d;
  es_et[pos] = et[e];
  es_eid[pos] = e;
}

// ---- bf16 split conversions ----
// x: [total] fp32 -> hi/lo bf16, 8 elems/thread
__global__ __launch_bounds__(256) void convx_kernel(const float* __restrict__ in,
                                                    unsigned short* __restrict__ hi,
                                                    unsigned short* __restrict__ lo,
                                                    int total8) {
  int i = blockIdx.x * 256 + threadIdx.x;
  if (i >= total8) return;
  const float4* p = (const float4*)in + (size_t)i * 2;
  float4 a = p[0], b = p[1];
  float v[8] = {a.x, a.y, a.z, a.w, b.x, b.y, b.z, b.w};
  bf16x8 hv, lv;
#pragma unroll
  for (int j = 0; j < 8; ++j) {
    unsigned short h, l;
    bf16split(v[j], h, l);
    hv[j] = (short)h; lv[j] = (short)l;
  }
  *(bf16x8*)(hi + (size_t)i * 8) = hv;
  *(bf16x8*)(lo + (size_t)i * 8) = lv;
}

// w [r][f][o] fp32 -> transposed hi/lo bf16 [r][o][f]
__global__ void convw_kernel(const float* __restrict__ w,
                             unsigned short* __restrict__ hiT,
                             unsigned short* __restrict__ loT) {
  int f = blockIdx.x, r = blockIdx.y, o = threadIdx.x;
  float v = w[((size_t)r * 128 + f) * 128 + o];
  unsigned short h, l;
  bf16split(v, h, l);
  hiT[((size_t)r * 128 + o) * 128 + f] = h;
  loT[((size_t)r * 128 + o) * 128 + f] = l;
}

// ---- proj via MFMA: xw[r,n,o] = sum_f x[n,f] w[r,f,o] ----
// grid (R, ceil(N/128)), block 256 = 4 waves. Wave wv: nodes [nb+wv*32, +32), all 128 o.
// D[m=o][n=node]: A = w^T (hi/lo), B = x (hi/lo). No LDS, no barriers.
__global__ __launch_bounds__(256, 4) void proj_mfma_kernel(
    const unsigned short* __restrict__ xhi, const unsigned short* __restrict__ xlo,
    const unsigned short* __restrict__ whiT, const unsigned short* __restrict__ wloT,
    float* __restrict__ xw, int N) {
  int r = blockIdx.x;
  int nb = blockIdx.y * 128;
  int wv = threadIdx.x >> 6;
  int lane = threadIdx.x & 63;
  int c = lane & 15, q = lane >> 4;
  int nodebase = nb + wv * 32;
  int n0 = nodebase + c;
  int n1 = nodebase + 16 + c;
  int n0c = n0 < N ? n0 : N - 1;
  int n1c = n1 < N ? n1 : N - 1;
  const unsigned short* wh = whiT + (size_t)r * (128 * 128);
  const unsigned short* wl = wloT + (size_t)r * (128 * 128);

  f32x4 acc[8][2];
#pragma unroll
  for (int ot = 0; ot < 8; ++ot)
#pragma unroll
    for (int nt = 0; nt < 2; ++nt) acc[ot][nt] = (f32x4){0.f, 0.f, 0.f, 0.f};

  for (int kc = 0; kc < 4; ++kc) {
    int k0 = kc * 32 + q * 8;
    bf16x8 b0h = *(const bf16x8*)(xhi + (size_t)n0c * 128 + k0);
    bf16x8 b0l = *(const bf16x8*)(xlo + (size_t)n0c * 128 + k0);
    bf16x8 b1h = *(const bf16x8*)(xhi + (size_t)n1c * 128 + k0);
    bf16x8 b1l = *(const bf16x8*)(xlo + (size_t)n1c * 128 + k0);
#pragma unroll
    for (int ot = 0; ot < 8; ++ot) {
      size_t ao = (size_t)(ot * 16 + c) * 128 + k0;
      bf16x8 ah = *(const bf16x8*)(wh + ao);
      bf16x8 al = *(const bf16x8*)(wl + ao);
      acc[ot][0] = __builtin_amdgcn_mfma_f32_16x16x32_bf16(ah, b0h, acc[ot][0], 0, 0, 0);
      acc[ot][0] = __builtin_amdgcn_mfma_f32_16x16x32_bf16(ah, b0l, acc[ot][0], 0, 0, 0);
      acc[ot][0] = __builtin_amdgcn_mfma_f32_16x16x32_bf16(al, b0h, acc[ot][0], 0, 0, 0);
      acc[ot][1] = __builtin_amdgcn_mfma_f32_16x16x32_bf16(ah, b1h, acc[ot][1], 0, 0, 0);
      acc[ot][1] = __builtin_amdgcn_mfma_f32_16x16x32_bf16(ah, b1l, acc[ot][1], 0, 0, 0);
      acc[ot][1] = __builtin_amdgcn_mfma_f32_16x16x32_bf16(al, b1h, acc[ot][1], 0, 0, 0);
    }
  }

  // D: col=lane&15 -> node within tile; row=q*4+reg -> o within tile
#pragma unroll
  for (int nt = 0; nt < 2; ++nt) {
    int n = nodebase + nt * 16 + c;
    if (n < N) {
      float* base = xw + ((size_t)r * N + n) * 128 + q * 4;
#pragma unroll
      for (int ot = 0; ot < 8; ++ot)
        *(f32x4*)(base + ot * 16) = acc[ot][nt];
    }
  }
}

// qn[row,h], kn[row,h] for row in [0, R*N): 64 rows/block, 4 threads/row
__global__ __launch_bounds__(256) void qk_kernel(const float* __restrict__ xw,
                                                 const float* __restrict__ q,
                                                 const float* __restrict__ k,
                                                 float* __restrict__ qn,
                                                 float* __restrict__ kn, int total) {
  __shared__ float sx[64 * 132];
  __shared__ float sq[512];
  __shared__ float sk[512];
  int rb = blockIdx.x * 64;
  int t = threadIdx.x;
  if (t < 128) ((float4*)sq)[t] = ((const float4*)q)[t];
  else if (t < 256) ((float4*)sk)[t - 128] = ((const float4*)k)[t - 128];
  int nrow = total - rb; if (nrow > 64) nrow = 64;
  const float4* s4 = (const float4*)(xw + (size_t)rb * 128);
  for (int i = t; i < nrow * 32; i += 256) {
    ((float4*)sx)[(i >> 5) * 33 + (i & 31)] = s4[i];
  }
  __syncthreads();
  int rl = t >> 2, l = t & 3;
  float aq[4] = {0, 0, 0, 0}, ak[4] = {0, 0, 0, 0};
  for (int i = 0; i < 32; ++i) {
    int o = l + 4 * i;
    float xv = sx[rl * 132 + o];
#pragma unroll
    for (int h = 0; h < 4; ++h) {
      aq[h] += xv * sq[o * 4 + h];
      ak[h] += xv * sk[o * 4 + h];
    }
  }
#pragma unroll
  for (int h = 0; h < 4; ++h) {
    aq[h] += __shfl_xor(aq[h], 1); aq[h] += __shfl_xor(aq[h], 2);
    ak[h] += __shfl_xor(ak[h], 1); ak[h] += __shfl_xor(ak[h], 2);
  }
  int row = rb + rl;
  if (l == 0 && row < total) {
    *(float4*)(qn + (size_t)row * 4) = make_float4(aq[0], aq[1], aq[2], aq[3]);
    *(float4*)(kn + (size_t)row * 4) = make_float4(ak[0], ak[1], ak[2], ak[3]);
  }
}

// ek[e,h] = sum_{f<16} ea[e,f]*lee[f,h]
__global__ __launch_bounds__(256) void ek_kernel(const float* __restrict__ ea,
                                                 const float* __restrict__ lee,
                                                 float* __restrict__ ek, int E) {
  __shared__ float sl[64];
  if (threadIdx.x < 64) sl[threadIdx.x] = lee[threadIdx.x];
  __syncthreads();
  int e = blockIdx.x * 256 + threadIdx.x;
  if (e >= E) return;
  const float4* a4 = (const float4*)(ea + (size_t)e * 16);
  float acc[4] = {0, 0, 0, 0};
#pragma unroll
  for (int i = 0; i < 4; ++i) {
    float4 v = a4[i];
    int f = i * 4;
#pragma unroll
    for (int h = 0; h < 4; ++h) {
      acc[h] += v.x * sl[f * 4 + h] + v.y * sl[(f + 1) * 4 + h] +
                v.z * sl[(f + 2) * 4 + h] + v.w * sl[(f + 3) * 4 + h];
    }
  }
  *(float4*)(ek + (size_t)e * 4) = make_float4(acc[0], acc[1], acc[2], acc[3]);
}

// alpha in dst-sorted order
__global__ __launch_bounds__(256) void alpha_kernel(
    const int* __restrict__ es_src, const int* __restrict__ es_dst,
    const int* __restrict__ es_et, const int* __restrict__ es_eid,
    const float* __restrict__ qn, const float* __restrict__ kn,
    const float* __restrict__ ek, float* __restrict__ alpha_s, int E, int N) {
  int i = blockIdx.x * 256 + threadIdx.x;
  if (i >= E) return;
  int s = es_src[i], d = es_dst[i], et = es_et[i], e = es_eid[i];
  float4 qv = *(const float4*)(qn + ((size_t)et * N + d) * 4);
  float4 kv = *(const float4*)(kn + ((size_t)et * N + s) * 4);
  float4 ev = *(const float4*)(ek + (size_t)e * 4);
  float a0 = qv.x + kv.x + ev.x, a1 = qv.y + kv.y + ev.y;
  float a2 = qv.z + kv.z + ev.z, a3 = qv.w + kv.w + ev.w;
  a0 = a0 > 0.f ? a0 : NEG_SLOPE * a0;
  a1 = a1 > 0.f ? a1 : NEG_SLOPE * a1;
  a2 = a2 > 0.f ? a2 : NEG_SLOPE * a2;
  a3 = a3 > 0.f ? a3 : NEG_SLOPE * a3;
  *(float4*)(alpha_s + (size_t)i * 4) = make_float4(a0, a1, a2, a3);
}

// fused softmax + gather-aggregate + epilogue. One wave per dst node.
__global__ __launch_bounds__(256) void agg_kernel(
    const int* __restrict__ es_src, const int* __restrict__ es_et,
    const int* __restrict__ row_start, const float* __restrict__ alpha_s,
    const float* __restrict__ xw, const float* __restrict__ bias,
    float* __restrict__ out, int N, int concat) {
  int d = blockIdx.x * 4 + (threadIdx.x >> 6);
  if (d >= N) return;
  int lane = threadIdx.x & 63;
  int rs = row_start[d], re = row_start[d + 1];

  float4 mx = make_float4(-1e30f, -1e30f, -1e30f, -1e30f);
  for (int i = rs + lane; i < re; i += 64) {
    float4 a = ((const float4*)alpha_s)[i];
    mx.x = fmaxf(mx.x, a.x); mx.y = fmaxf(mx.y, a.y);
    mx.z = fmaxf(mx.z, a.z); mx.w = fmaxf(mx.w, a.w);
  }
#pragma unroll
  for (int o = 32; o >= 1; o >>= 1) {
    mx.x = fmaxf(mx.x, __shfl_xor(mx.x, o));
    mx.y = fmaxf(mx.y, __shfl_xor(mx.y, o));
    mx.z = fmaxf(mx.z, __shfl_xor(mx.z, o));
    mx.w = fmaxf(mx.w, __shfl_xor(mx.w, o));
  }
  float4 sm = make_float4(0.f, 0.f, 0.f, 0.f);
  for (int i = rs + lane; i < re; i += 64) {
    float4 a = ((const float4*)alpha_s)[i];
    sm.x += __expf(a.x - mx.x); sm.y += __expf(a.y - mx.y);
    sm.z += __expf(a.z - mx.z); sm.w += __expf(a.w - mx.w);
  }
#pragma unroll
  for (int o = 32; o >= 1; o >>= 1) {
    sm.x += __shfl_xor(sm.x, o); sm.y += __shfl_xor(sm.y, o);
    sm.z += __shfl_xor(sm.z, o); sm.w += __shfl_xor(sm.w, o);
  }
  int h = lane >> 4;
  float mxh = (h == 0) ? mx.x : (h == 1) ? mx.y : (h == 2) ? mx.z : mx.w;
  float smh = (h == 0) ? sm.x : (h == 1) ? sm.y : (h == 2) ? sm.z : sm.w;
  float rden = 1.f / (smh + SOFT_EPS);

  float ax = 0.f, ay = 0.f;
  for (int i = rs; i < re; ++i) {
    int s = es_src[i], et = es_et[i];
    float w = __expf(alpha_s[(size_t)i * 4 + h] - mxh) * rden;
    float2 xv = *(const float2*)(xw + ((size_t)et * N + s) * 128 + lane * 2);
    ax += w * xv.x; ay += w * xv.y;
  }

  if (concat) {
    float2 bv = *(const float2*)(bias + lane * 2);
    float vx = ax + bv.x, vy = ay + bv.y;
    vx = vx > 0.f ? vx : 0.f;
    vy = vy > 0.f ? vy : 0.f;
    *(float2*)(out + (size_t)d * 128 + lane * 2) = make_float2(vx, vy);
  } else {
#pragma unroll
    for (int o = 16; o <= 32; o <<= 1) {
      ax += __shfl_xor(ax, o);
      ay += __shfl_xor(ay, o);
    }
    if (lane < 16) {
      float2 bv = *(const float2*)(bias + lane * 2);
      *(float2*)(out + (size_t)d * 32 + lane * 2) =
          make_float2(0.25f * ax + bv.x, 0.25f * ay + bv.y);
    }
  }
}

extern "C" void kernel_launch(void* const* d_in, const int* in_sizes, int n_in,
                              void* d_out, int out_size, void* d_ws, size_t ws_size,
                              hipStream_t stream) {
  const float* x   = (const float*)d_in[0];
  const int*   ei  = (const int*)d_in[1];
  const float* ea  = (const float*)d_in[2];
  const int*   etp = (const int*)d_in[3];
  const float* w1  = (const float*)d_in[4];
  const float* q1  = (const float*)d_in[5];
  const float* k1  = (const float*)d_in[6];
  const float* e1  = (const float*)d_in[7];
  const float* le1 = (const float*)d_in[8];
  const float* b1  = (const float*)d_in[9];
  const float* w3  = (const float*)d_in[10];
  const float* q3  = (const float*)d_in[11];
  const float* k3  = (const float*)d_in[12];
  const float* e3  = (const float*)d_in[13];
  const float* le3 = (const float*)d_in[14];
  const float* b3  = (const float*)d_in[15];
  const int N = in_sizes[0] / 128;
  const int E = in_sizes[3];
  const int* srcp = ei;
  const int* dstp = ei + E;

  float* ws   = (float*)d_ws;
  float* xw   = ws;                                  // 4*N*128
  float* qn   = xw + (size_t)4 * N * 128;            // 4*N*4
  float* kn   = qn + (size_t)4 * N * 4;              // 4*N*4
  float* ekb  = kn + (size_t)4 * N * 4;              // E*4
  float* alph = ekb + (size_t)E * 4;                 // E*4
  float* hbuf = alph + (size_t)E * 4;                // N*128
  float* leeb = hbuf + (size_t)N * 128;              // 128
  int* deg      = (int*)(leeb + 128);                // N
  int* rowst    = deg + N;                           // N+1
  int* cursor   = rowst + N + 1;                     // N
  int* es_src   = cursor + N;                        // E
  int* es_dst   = es_src + E;                        // E
  int* es_et    = es_dst + E;                        // E
  int* es_eid   = es_et + E;                         // E
  int* bsum     = es_eid + E;                        // 256
  int* boff     = bsum + 256;                        // 256
  uintptr_t pa = (uintptr_t)(boff + 256);
  pa = (pa + 255) & ~(uintptr_t)255;                 // 16B+ alignment for bf16x8
  unsigned short* xhi  = (unsigned short*)pa;        // N*128
  unsigned short* xlo  = xhi + (size_t)N * 128;      // N*128
  unsigned short* whiT = xlo + (size_t)N * 128;      // 4*128*128
  unsigned short* wloT = whiT + 4 * 128 * 128;       // 4*128*128
  (void)ws_size; (void)n_in; (void)out_size;

  int qkb  = (4 * N + 63) / 64;
  int eb   = (E + 255) / 256;
  int nb4  = (N + 3) / 4;
  int nbs  = (N + 1023) / 1024;
  int pgy  = (N + 127) / 128;
  int cxb  = (N * 128 / 8 + 255) / 256;

  hipMemsetAsync(deg, 0, (size_t)N * sizeof(int), stream);
  hist_kernel<<<eb, 256, 0, stream>>>(dstp, deg, E);
  scanA_kernel<<<nbs, 256, 0, stream>>>(deg, bsum, N);
  scanB_kernel<<<1, 256, 0, stream>>>(bsum, boff, rowst, nbs, N);
  scanC_kernel<<<nbs, 256, 0, stream>>>(deg, boff, rowst, cursor, N);
  scatter_kernel<<<eb, 256, 0, stream>>>(srcp, dstp, etp, cursor,
                                         es_src, es_dst, es_et, es_eid, E);
  lee_kernel<<<1, 128, 0, stream>>>(le1, e1, le3, e3, leeb);

  for (int layer = 0; layer < 2; ++layer) {
    const float* xin = layer ? hbuf : x;
    const float* w   = layer ? w3 : w1;
    const float* q   = layer ? q3 : q1;
    const float* k   = layer ? k3 : k1;
    const float* leep = leeb + (layer ? 64 : 0);
    const float* bias = layer ? b3 : b1;
    float* outp = layer ? (float*)d_out : hbuf;

    convx_kernel<<<cxb, 256, 0, stream>>>(xin, xhi, xlo, N * 128 / 8);
    convw_kernel<<<dim3(128, 4), 128, 0, stream>>>(w, whiT, wloT);
    proj_mfma_kernel<<<dim3(4, pgy), 256, 0, stream>>>(xhi, xlo, whiT, wloT, xw, N);
    qk_kernel<<<qkb, 256, 0, stream>>>(xw, q, k, qn, kn, 4 * N);
    ek_kernel<<<eb, 256, 0, stream>>>(ea, leep, ekb, E);
    alpha_kernel<<<eb, 256, 0, stream>>>(es_src, es_dst, es_et, es_eid,
                                         qn, kn, ekb, alph, E, N);
    agg_kernel<<<nb4, 256, 0, stream>>>(es_src, es_et, rowst, alph, xw,
                                        bias, outp, N, layer == 0 ? 1 : 0);
  }
}

// Round 6
// 683.252 us; speedup vs baseline: 1.0960x; 1.0960x over previous
//
#include <hip/hip_runtime.h>

// RGATNetwork: 2x RGATConv (R=4, H=4, C=32, HC=128, F_E=16) on N=50k nodes, E=800k edges.
// R6: agg_kernel gather restructured for MLP: pass 2 stores exp back into alpha_s
// (no exp in gather), gather uses 32 lanes/edge x float4 (16 B/lane), 4 edges per
// unrolled iteration (2 independent 1 KB loads in flight), rden hoisted.
// Rest unchanged from R5 (split-bf16 MFMA proj, CSR gather, hierarchical scan).

#define NEG_SLOPE 0.2f
#define SOFT_EPS 1e-16f

typedef __attribute__((ext_vector_type(8))) short bf16x8;
typedef __attribute__((ext_vector_type(4))) float f32x4;

__device__ __forceinline__ void bf16split(float f, unsigned short& h, unsigned short& l) {
  unsigned u = __float_as_uint(f);
  unsigned r = u + 0x7FFFu + ((u >> 16) & 1u);
  h = (unsigned short)(r >> 16);
  float fh = __uint_as_float(((unsigned)h) << 16);
  float d = f - fh;
  unsigned u2 = __float_as_uint(d);
  unsigned r2 = u2 + 0x7FFFu + ((u2 >> 16) & 1u);
  l = (unsigned short)(r2 >> 16);
}

// lee[f,h] = sum_o le[f,o]*e[o,h]  for both layers (t<64: layer1, t>=64: layer3)
__global__ void lee_kernel(const float* __restrict__ le1, const float* __restrict__ e1,
                           const float* __restrict__ le3, const float* __restrict__ e3,
                           float* __restrict__ lee) {
  int t = threadIdx.x;
  const float* le = (t < 64) ? le1 : le3;
  const float* ee = (t < 64) ? e1 : e3;
  int u = t & 63, f = u >> 2, h = u & 3;
  float acc = 0.f;
  for (int o = 0; o < 128; ++o) acc += le[f * 128 + o] * ee[o * 4 + h];
  lee[t] = acc;
}

// ---- CSR build ----
__global__ __launch_bounds__(256) void hist_kernel(const int* __restrict__ dst,
                                                   int* __restrict__ deg, int E) {
  int e = blockIdx.x * 256 + threadIdx.x;
  if (e < E) atomicAdd(&deg[dst[e]], 1);
}

__global__ __launch_bounds__(256) void scanA_kernel(const int* __restrict__ deg,
                                                    int* __restrict__ bsum, int N) {
  int b = blockIdx.x, t = threadIdx.x;
  int base = b * 1024 + t * 4;
  int s = 0;
#pragma unroll
  for (int j = 0; j < 4; ++j) {
    int i = base + j;
    if (i < N) s += deg[i];
  }
#pragma unroll
  for (int o = 1; o < 64; o <<= 1) s += __shfl_xor(s, o);
  __shared__ int wsum[4];
  if ((t & 63) == 0) wsum[t >> 6] = s;
  __syncthreads();
  if (t == 0) bsum[b] = wsum[0] + wsum[1] + wsum[2] + wsum[3];
}

__global__ __launch_bounds__(256) void scanB_kernel(const int* __restrict__ bsum,
                                                    int* __restrict__ boff,
                                                    int* __restrict__ row_start,
                                                    int nb, int N) {
  int t = threadIdx.x;
  int v = (t < nb) ? bsum[t] : 0;
  int inc = v;
#pragma unroll
  for (int o = 1; o < 64; o <<= 1) {
    int u = __shfl_up(inc, o);
    if ((t & 63) >= o) inc += u;
  }
  __shared__ int wt[4];
  if ((t & 63) == 63) wt[t >> 6] = inc;
  __syncthreads();
  int add = 0;
  for (int wv = 0; wv < (t >> 6); ++wv) add += wt[wv];
  inc += add;
  if (t < nb) boff[t] = inc - v;
  if (t == 255) row_start[N] = inc;
}

__global__ __launch_bounds__(256) void scanC_kernel(const int* __restrict__ deg,
                                                    const int* __restrict__ boff,
                                                    int* __restrict__ row_start,
                                                    int* __restrict__ cursor, int N) {
  int b = blockIdx.x, t = threadIdx.x;
  int base = b * 1024 + t * 4;
  int d[4];
  int s = 0;
#pragma unroll
  for (int j = 0; j < 4; ++j) {
    int i = base + j;
    d[j] = (i < N) ? deg[i] : 0;
    s += d[j];
  }
  int inc = s;
#pragma unroll
  for (int o = 1; o < 64; o <<= 1) {
    int u = __shfl_up(inc, o);
    if ((t & 63) >= o) inc += u;
  }
  __shared__ int wt[4];
  if ((t & 63) == 63) wt[t >> 6] = inc;
  __syncthreads();
  int add = boff[b];
  for (int wv = 0; wv < (t >> 6); ++wv) add += wt[wv];
  int off = add + inc - s;
#pragma unroll
  for (int j = 0; j < 4; ++j) {
    int i = base + j;
    if (i < N) {
      row_start[i] = off;
      cursor[i] = off;
      off += d[j];
    }
  }
}

__global__ __launch_bounds__(256) void scatter_kernel(
    const int* __restrict__ src, const int* __restrict__ dst, const int* __restrict__ et,
    int* __restrict__ cursor, int* __restrict__ es_src, int* __restrict__ es_dst,
    int* __restrict__ es_et, int* __restrict__ es_eid, int E) {
  int e = blockIdx.x * 256 + threadIdx.x;
  if (e >= E) return;
  int d = dst[e];
  int pos = atomicAdd(&cursor[d], 1);
  es_src[pos] = src[e];
  es_dst[pos] = d;
  es_et[pos] = et[e];
  es_eid[pos] = e;
}

// ---- bf16 split conversions ----
__global__ __launch_bounds__(256) void convx_kernel(const float* __restrict__ in,
                                                    unsigned short* __restrict__ hi,
                                                    unsigned short* __restrict__ lo,
                                                    int total8) {
  int i = blockIdx.x * 256 + threadIdx.x;
  if (i >= total8) return;
  const float4* p = (const float4*)in + (size_t)i * 2;
  float4 a = p[0], b = p[1];
  float v[8] = {a.x, a.y, a.z, a.w, b.x, b.y, b.z, b.w};
  bf16x8 hv, lv;
#pragma unroll
  for (int j = 0; j < 8; ++j) {
    unsigned short h, l;
    bf16split(v[j], h, l);
    hv[j] = (short)h; lv[j] = (short)l;
  }
  *(bf16x8*)(hi + (size_t)i * 8) = hv;
  *(bf16x8*)(lo + (size_t)i * 8) = lv;
}

__global__ void convw_kernel(const float* __restrict__ w,
                             unsigned short* __restrict__ hiT,
                             unsigned short* __restrict__ loT) {
  int f = blockIdx.x, r = blockIdx.y, o = threadIdx.x;
  float v = w[((size_t)r * 128 + f) * 128 + o];
  unsigned short h, l;
  bf16split(v, h, l);
  hiT[((size_t)r * 128 + o) * 128 + f] = h;
  loT[((size_t)r * 128 + o) * 128 + f] = l;
}

// ---- proj via MFMA (split-bf16, no LDS, no barriers) ----
__global__ __launch_bounds__(256, 4) void proj_mfma_kernel(
    const unsigned short* __restrict__ xhi, const unsigned short* __restrict__ xlo,
    const unsigned short* __restrict__ whiT, const unsigned short* __restrict__ wloT,
    float* __restrict__ xw, int N) {
  int r = blockIdx.x;
  int nb = blockIdx.y * 128;
  int wv = threadIdx.x >> 6;
  int lane = threadIdx.x & 63;
  int c = lane & 15, q = lane >> 4;
  int nodebase = nb + wv * 32;
  int n0 = nodebase + c;
  int n1 = nodebase + 16 + c;
  int n0c = n0 < N ? n0 : N - 1;
  int n1c = n1 < N ? n1 : N - 1;
  const unsigned short* wh = whiT + (size_t)r * (128 * 128);
  const unsigned short* wl = wloT + (size_t)r * (128 * 128);

  f32x4 acc[8][2];
#pragma unroll
  for (int ot = 0; ot < 8; ++ot)
#pragma unroll
    for (int nt = 0; nt < 2; ++nt) acc[ot][nt] = (f32x4){0.f, 0.f, 0.f, 0.f};

  for (int kc = 0; kc < 4; ++kc) {
    int k0 = kc * 32 + q * 8;
    bf16x8 b0h = *(const bf16x8*)(xhi + (size_t)n0c * 128 + k0);
    bf16x8 b0l = *(const bf16x8*)(xlo + (size_t)n0c * 128 + k0);
    bf16x8 b1h = *(const bf16x8*)(xhi + (size_t)n1c * 128 + k0);
    bf16x8 b1l = *(const bf16x8*)(xlo + (size_t)n1c * 128 + k0);
#pragma unroll
    for (int ot = 0; ot < 8; ++ot) {
      size_t ao = (size_t)(ot * 16 + c) * 128 + k0;
      bf16x8 ah = *(const bf16x8*)(wh + ao);
      bf16x8 al = *(const bf16x8*)(wl + ao);
      acc[ot][0] = __builtin_amdgcn_mfma_f32_16x16x32_bf16(ah, b0h, acc[ot][0], 0, 0, 0);
      acc[ot][0] = __builtin_amdgcn_mfma_f32_16x16x32_bf16(ah, b0l, acc[ot][0], 0, 0, 0);
      acc[ot][0] = __builtin_amdgcn_mfma_f32_16x16x32_bf16(al, b0h, acc[ot][0], 0, 0, 0);
      acc[ot][1] = __builtin_amdgcn_mfma_f32_16x16x32_bf16(ah, b1h, acc[ot][1], 0, 0, 0);
      acc[ot][1] = __builtin_amdgcn_mfma_f32_16x16x32_bf16(ah, b1l, acc[ot][1], 0, 0, 0);
      acc[ot][1] = __builtin_amdgcn_mfma_f32_16x16x32_bf16(al, b1h, acc[ot][1], 0, 0, 0);
    }
  }

#pragma unroll
  for (int nt = 0; nt < 2; ++nt) {
    int n = nodebase + nt * 16 + c;
    if (n < N) {
      float* base = xw + ((size_t)r * N + n) * 128 + q * 4;
#pragma unroll
      for (int ot = 0; ot < 8; ++ot)
        *(f32x4*)(base + ot * 16) = acc[ot][nt];
    }
  }
}

// qn[row,h], kn[row,h] for row in [0, R*N): 64 rows/block, 4 threads/row
__global__ __launch_bounds__(256) void qk_kernel(const float* __restrict__ xw,
                                                 const float* __restrict__ q,
                                                 const float* __restrict__ k,
                                                 float* __restrict__ qn,
                                                 float* __restrict__ kn, int total) {
  __shared__ float sx[64 * 132];
  __shared__ float sq[512];
  __shared__ float sk[512];
  int rb = blockIdx.x * 64;
  int t = threadIdx.x;
  if (t < 128) ((float4*)sq)[t] = ((const float4*)q)[t];
  else if (t < 256) ((float4*)sk)[t - 128] = ((const float4*)k)[t - 128];
  int nrow = total - rb; if (nrow > 64) nrow = 64;
  const float4* s4 = (const float4*)(xw + (size_t)rb * 128);
  for (int i = t; i < nrow * 32; i += 256) {
    ((float4*)sx)[(i >> 5) * 33 + (i & 31)] = s4[i];
  }
  __syncthreads();
  int rl = t >> 2, l = t & 3;
  float aq[4] = {0, 0, 0, 0}, ak[4] = {0, 0, 0, 0};
  for (int i = 0; i < 32; ++i) {
    int o = l + 4 * i;
    float xv = sx[rl * 132 + o];
#pragma unroll
    for (int h = 0; h < 4; ++h) {
      aq[h] += xv * sq[o * 4 + h];
      ak[h] += xv * sk[o * 4 + h];
    }
  }
#pragma unroll
  for (int h = 0; h < 4; ++h) {
    aq[h] += __shfl_xor(aq[h], 1); aq[h] += __shfl_xor(aq[h], 2);
    ak[h] += __shfl_xor(ak[h], 1); ak[h] += __shfl_xor(ak[h], 2);
  }
  int row = rb + rl;
  if (l == 0 && row < total) {
    *(float4*)(qn + (size_t)row * 4) = make_float4(aq[0], aq[1], aq[2], aq[3]);
    *(float4*)(kn + (size_t)row * 4) = make_float4(ak[0], ak[1], ak[2], ak[3]);
  }
}

// ek[e,h] = sum_{f<16} ea[e,f]*lee[f,h]
__global__ __launch_bounds__(256) void ek_kernel(const float* __restrict__ ea,
                                                 const float* __restrict__ lee,
                                                 float* __restrict__ ek, int E) {
  __shared__ float sl[64];
  if (threadIdx.x < 64) sl[threadIdx.x] = lee[threadIdx.x];
  __syncthreads();
  int e = blockIdx.x * 256 + threadIdx.x;
  if (e >= E) return;
  const float4* a4 = (const float4*)(ea + (size_t)e * 16);
  float acc[4] = {0, 0, 0, 0};
#pragma unroll
  for (int i = 0; i < 4; ++i) {
    float4 v = a4[i];
    int f = i * 4;
#pragma unroll
    for (int h = 0; h < 4; ++h) {
      acc[h] += v.x * sl[f * 4 + h] + v.y * sl[(f + 1) * 4 + h] +
                v.z * sl[(f + 2) * 4 + h] + v.w * sl[(f + 3) * 4 + h];
    }
  }
  *(float4*)(ek + (size_t)e * 4) = make_float4(acc[0], acc[1], acc[2], acc[3]);
}

// alpha in dst-sorted order
__global__ __launch_bounds__(256) void alpha_kernel(
    const int* __restrict__ es_src, const int* __restrict__ es_dst,
    const int* __restrict__ es_et, const int* __restrict__ es_eid,
    const float* __restrict__ qn, const float* __restrict__ kn,
    const float* __restrict__ ek, float* __restrict__ alpha_s, int E, int N) {
  int i = blockIdx.x * 256 + threadIdx.x;
  if (i >= E) return;
  int s = es_src[i], d = es_dst[i], et = es_et[i], e = es_eid[i];
  float4 qv = *(const float4*)(qn + ((size_t)et * N + d) * 4);
  float4 kv = *(const float4*)(kn + ((size_t)et * N + s) * 4);
  float4 ev = *(const float4*)(ek + (size_t)e * 4);
  float a0 = qv.x + kv.x + ev.x, a1 = qv.y + kv.y + ev.y;
  float a2 = qv.z + kv.z + ev.z, a3 = qv.w + kv.w + ev.w;
  a0 = a0 > 0.f ? a0 : NEG_SLOPE * a0;
  a1 = a1 > 0.f ? a1 : NEG_SLOPE * a1;
  a2 = a2 > 0.f ? a2 : NEG_SLOPE * a2;
  a3 = a3 > 0.f ? a3 : NEG_SLOPE * a3;
  *(float4*)(alpha_s + (size_t)i * 4) = make_float4(a0, a1, a2, a3);
}

// fused softmax + gather-aggregate + epilogue. One wave per dst node.
// Pass 2 overwrites alpha_s with exp values (wave exclusively owns [rs,re)).
// Gather: 32 lanes/edge, float4/lane, 4 edges per unrolled iteration.
__global__ __launch_bounds__(256) void agg_kernel(
    const int* __restrict__ es_src, const int* __restrict__ es_et,
    const int* __restrict__ row_start, float* __restrict__ alpha_s,
    const float* __restrict__ xw, const float* __restrict__ bias,
    float* __restrict__ out, int N, int concat) {
  int d = blockIdx.x * 4 + (threadIdx.x >> 6);
  if (d >= N) return;
  int lane = threadIdx.x & 63;
  int rs = row_start[d], re = row_start[d + 1];

  // pass 1: per-head max
  float4 mx = make_float4(-1e30f, -1e30f, -1e30f, -1e30f);
  for (int i = rs + lane; i < re; i += 64) {
    float4 a = ((const float4*)alpha_s)[i];
    mx.x = fmaxf(mx.x, a.x); mx.y = fmaxf(mx.y, a.y);
    mx.z = fmaxf(mx.z, a.z); mx.w = fmaxf(mx.w, a.w);
  }
#pragma unroll
  for (int o = 32; o >= 1; o >>= 1) {
    mx.x = fmaxf(mx.x, __shfl_xor(mx.x, o));
    mx.y = fmaxf(mx.y, __shfl_xor(mx.y, o));
    mx.z = fmaxf(mx.z, __shfl_xor(mx.z, o));
    mx.w = fmaxf(mx.w, __shfl_xor(mx.w, o));
  }
  // pass 2: sum-exp, write exp back
  float4 sm = make_float4(0.f, 0.f, 0.f, 0.f);
  for (int i = rs + lane; i < re; i += 64) {
    float4 a = ((float4*)alpha_s)[i];
    a.x = __expf(a.x - mx.x); a.y = __expf(a.y - mx.y);
    a.z = __expf(a.z - mx.z); a.w = __expf(a.w - mx.w);
    ((float4*)alpha_s)[i] = a;
    sm.x += a.x; sm.y += a.y; sm.z += a.z; sm.w += a.w;
  }
#pragma unroll
  for (int o = 32; o >= 1; o >>= 1) {
    sm.x += __shfl_xor(sm.x, o); sm.y += __shfl_xor(sm.y, o);
    sm.z += __shfl_xor(sm.z, o); sm.w += __shfl_xor(sm.w, o);
  }

  int half = lane >> 5;     // which edge of the pair
  int cl = lane & 31;       // float4 slot within 128-wide row
  int h = cl >> 3;          // head
  float smh = (h == 0) ? sm.x : (h == 1) ? sm.y : (h == 2) ? sm.z : sm.w;
  float rden = 1.f / (smh + SOFT_EPS);

  // pass 3: gather. 2 edges per wave-step, unrolled x2 (4 edges/iter).
  float4 acc = make_float4(0.f, 0.f, 0.f, 0.f);
  int base = rs;
  for (; base + 4 <= re; base += 4) {
    int e0 = base + half;
    int e1 = base + 2 + half;
    int s0 = es_src[e0], t0 = es_et[e0];
    int s1 = es_src[e1], t1 = es_et[e1];
    float w0 = alpha_s[(size_t)e0 * 4 + h];
    float w1 = alpha_s[(size_t)e1 * 4 + h];
    float4 x0 = *(const float4*)(xw + ((size_t)t0 * N + s0) * 128 + cl * 4);
    float4 x1 = *(const float4*)(xw + ((size_t)t1 * N + s1) * 128 + cl * 4);
    acc.x += w0 * x0.x; acc.y += w0 * x0.y; acc.z += w0 * x0.z; acc.w += w0 * x0.w;
    acc.x += w1 * x1.x; acc.y += w1 * x1.y; acc.z += w1 * x1.z; acc.w += w1 * x1.w;
  }
  for (; base < re; base += 2) {
    int e = base + half;
    if (e < re) {
      int s = es_src[e], t = es_et[e];
      float w = alpha_s[(size_t)e * 4 + h];
      float4 xv = *(const float4*)(xw + ((size_t)t * N + s) * 128 + cl * 4);
      acc.x += w * xv.x; acc.y += w * xv.y; acc.z += w * xv.z; acc.w += w * xv.w;
    }
  }
  // normalize, then combine the two edge-halves
  acc.x *= rden; acc.y *= rden; acc.z *= rden; acc.w *= rden;
  acc.x += __shfl_xor(acc.x, 32); acc.y += __shfl_xor(acc.y, 32);
  acc.z += __shfl_xor(acc.z, 32); acc.w += __shfl_xor(acc.w, 32);

  if (concat) {  // layer 1: relu(agg + b1) -> hbuf[d,128]
    if (half == 0) {
      float4 bv = ((const float4*)bias)[cl];
      float4 v = make_float4(acc.x + bv.x, acc.y + bv.y, acc.z + bv.z, acc.w + bv.w);
      v.x = v.x > 0.f ? v.x : 0.f;
      v.y = v.y > 0.f ? v.y : 0.f;
      v.z = v.z > 0.f ? v.z : 0.f;
      v.w = v.w > 0.f ? v.w : 0.f;
      ((float4*)(out + (size_t)d * 128))[cl] = v;
    }
  } else {       // layer 2: mean over 4 heads + b3 -> out[d,32]
    acc.x += __shfl_xor(acc.x, 8);  acc.y += __shfl_xor(acc.y, 8);
    acc.z += __shfl_xor(acc.z, 8);  acc.w += __shfl_xor(acc.w, 8);
    acc.x += __shfl_xor(acc.x, 16); acc.y += __shfl_xor(acc.y, 16);
    acc.z += __shfl_xor(acc.z, 16); acc.w += __shfl_xor(acc.w, 16);
    if (lane < 8) {
      float4 bv = ((const float4*)bias)[lane];
      float4 v = make_float4(0.25f * acc.x + bv.x, 0.25f * acc.y + bv.y,
                             0.25f * acc.z + bv.z, 0.25f * acc.w + bv.w);
      ((float4*)(out + (size_t)d * 32))[lane] = v;
    }
  }
}

extern "C" void kernel_launch(void* const* d_in, const int* in_sizes, int n_in,
                              void* d_out, int out_size, void* d_ws, size_t ws_size,
                              hipStream_t stream) {
  const float* x   = (const float*)d_in[0];
  const int*   ei  = (const int*)d_in[1];
  const float* ea  = (const float*)d_in[2];
  const int*   etp = (const int*)d_in[3];
  const float* w1  = (const float*)d_in[4];
  const float* q1  = (const float*)d_in[5];
  const float* k1  = (const float*)d_in[6];
  const float* e1  = (const float*)d_in[7];
  const float* le1 = (const float*)d_in[8];
  const float* b1  = (const float*)d_in[9];
  const float* w3  = (const float*)d_in[10];
  const float* q3  = (const float*)d_in[11];
  const float* k3  = (const float*)d_in[12];
  const float* e3  = (const float*)d_in[13];
  const float* le3 = (const float*)d_in[14];
  const float* b3  = (const float*)d_in[15];
  const int N = in_sizes[0] / 128;
  const int E = in_sizes[3];
  const int* srcp = ei;
  const int* dstp = ei + E;

  float* ws   = (float*)d_ws;
  float* xw   = ws;                                  // 4*N*128
  float* qn   = xw + (size_t)4 * N * 128;            // 4*N*4
  float* kn   = qn + (size_t)4 * N * 4;              // 4*N*4
  float* ekb  = kn + (size_t)4 * N * 4;              // E*4
  float* alph = ekb + (size_t)E * 4;                 // E*4
  float* hbuf = alph + (size_t)E * 4;                // N*128
  float* leeb = hbuf + (size_t)N * 128;              // 128
  int* deg      = (int*)(leeb + 128);                // N
  int* rowst    = deg + N;                           // N+1
  int* cursor   = rowst + N + 1;                     // N
  int* es_src   = cursor + N;                        // E
  int* es_dst   = es_src + E;                        // E
  int* es_et    = es_dst + E;                        // E
  int* es_eid   = es_et + E;                         // E
  int* bsum     = es_eid + E;                        // 256
  int* boff     = bsum + 256;                        // 256
  uintptr_t pa = (uintptr_t)(boff + 256);
  pa = (pa + 255) & ~(uintptr_t)255;
  unsigned short* xhi  = (unsigned short*)pa;        // N*128
  unsigned short* xlo  = xhi + (size_t)N * 128;      // N*128
  unsigned short* whiT = xlo + (size_t)N * 128;      // 4*128*128
  unsigned short* wloT = whiT + 4 * 128 * 128;       // 4*128*128
  (void)ws_size; (void)n_in; (void)out_size;

  int qkb  = (4 * N + 63) / 64;
  int eb   = (E + 255) / 256;
  int nb4  = (N + 3) / 4;
  int nbs  = (N + 1023) / 1024;
  int pgy  = (N + 127) / 128;
  int cxb  = (N * 128 / 8 + 255) / 256;

  hipMemsetAsync(deg, 0, (size_t)N * sizeof(int), stream);
  hist_kernel<<<eb, 256, 0, stream>>>(dstp, deg, E);
  scanA_kernel<<<nbs, 256, 0, stream>>>(deg, bsum, N);
  scanB_kernel<<<1, 256, 0, stream>>>(bsum, boff, rowst, nbs, N);
  scanC_kernel<<<nbs, 256, 0, stream>>>(deg, boff, rowst, cursor, N);
  scatter_kernel<<<eb, 256, 0, stream>>>(srcp, dstp, etp, cursor,
                                         es_src, es_dst, es_et, es_eid, E);
  lee_kernel<<<1, 128, 0, stream>>>(le1, e1, le3, e3, leeb);

  for (int layer = 0; layer < 2; ++layer) {
    const float* xin = layer ? hbuf : x;
    const float* w   = layer ? w3 : w1;
    const float* q   = layer ? q3 : q1;
    const float* k   = layer ? k3 : k1;
    const float* leep = leeb + (layer ? 64 : 0);
    const float* bias = layer ? b3 : b1;
    float* outp = layer ? (float*)d_out : hbuf;

    convx_kernel<<<cxb, 256, 0, stream>>>(xin, xhi, xlo, N * 128 / 8);
    convw_kernel<<<dim3(128, 4), 128, 0, stream>>>(w, whiT, wloT);
    proj_mfma_kernel<<<dim3(4, pgy), 256, 0, stream>>>(xhi, xlo, whiT, wloT, xw, N);
    qk_kernel<<<qkb, 256, 0, stream>>>(xw, q, k, qn, kn, 4 * N);
    ek_kernel<<<eb, 256, 0, stream>>>(ea, leep, ekb, E);
    alpha_kernel<<<eb, 256, 0, stream>>>(es_src, es_dst, es_et, es_eid,
                                         qn, kn, ekb, alph, E, N);
    agg_kernel<<<nb4, 256, 0, stream>>>(es_src, es_et, rowst, alph, xw,
                                        bias, outp, N, layer == 0 ? 1 : 0);
  }
}

// Round 7
// 610.606 us; speedup vs baseline: 1.2264x; 1.1190x over previous
//
#include <hip/hip_runtime.h>

// RGATNetwork: 2x RGATConv (R=4, H=4, C=32, HC=128, F_E=16) on N=50k nodes, E=800k edges.
// R7: proj_mfma stages w (hi+lo bf16) into LDS once per block in FRAGMENT-MAJOR
// order [(ot,kc,q)][c] -> every ds_read_b128 is 256B-contiguous per quarter
// (conflict-free, no padding, exactly 64 KB LDS). Single barrier; K-loop has
// no barriers; x fragments double-buffered from global.
// Rest unchanged from R6.

#define NEG_SLOPE 0.2f
#define SOFT_EPS 1e-16f

typedef __attribute__((ext_vector_type(8))) short bf16x8;
typedef __attribute__((ext_vector_type(4))) float f32x4;

__device__ __forceinline__ void bf16split(float f, unsigned short& h, unsigned short& l) {
  unsigned u = __float_as_uint(f);
  unsigned r = u + 0x7FFFu + ((u >> 16) & 1u);
  h = (unsigned short)(r >> 16);
  float fh = __uint_as_float(((unsigned)h) << 16);
  float d = f - fh;
  unsigned u2 = __float_as_uint(d);
  unsigned r2 = u2 + 0x7FFFu + ((u2 >> 16) & 1u);
  l = (unsigned short)(r2 >> 16);
}

// lee[f,h] = sum_o le[f,o]*e[o,h]  for both layers (t<64: layer1, t>=64: layer3)
__global__ void lee_kernel(const float* __restrict__ le1, const float* __restrict__ e1,
                           const float* __restrict__ le3, const float* __restrict__ e3,
                           float* __restrict__ lee) {
  int t = threadIdx.x;
  const float* le = (t < 64) ? le1 : le3;
  const float* ee = (t < 64) ? e1 : e3;
  int u = t & 63, f = u >> 2, h = u & 3;
  float acc = 0.f;
  for (int o = 0; o < 128; ++o) acc += le[f * 128 + o] * ee[o * 4 + h];
  lee[t] = acc;
}

// ---- CSR build ----
__global__ __launch_bounds__(256) void hist_kernel(const int* __restrict__ dst,
                                                   int* __restrict__ deg, int E) {
  int e = blockIdx.x * 256 + threadIdx.x;
  if (e < E) atomicAdd(&deg[dst[e]], 1);
}

__global__ __launch_bounds__(256) void scanA_kernel(const int* __restrict__ deg,
                                                    int* __restrict__ bsum, int N) {
  int b = blockIdx.x, t = threadIdx.x;
  int base = b * 1024 + t * 4;
  int s = 0;
#pragma unroll
  for (int j = 0; j < 4; ++j) {
    int i = base + j;
    if (i < N) s += deg[i];
  }
#pragma unroll
  for (int o = 1; o < 64; o <<= 1) s += __shfl_xor(s, o);
  __shared__ int wsum[4];
  if ((t & 63) == 0) wsum[t >> 6] = s;
  __syncthreads();
  if (t == 0) bsum[b] = wsum[0] + wsum[1] + wsum[2] + wsum[3];
}

__global__ __launch_bounds__(256) void scanB_kernel(const int* __restrict__ bsum,
                                                    int* __restrict__ boff,
                                                    int* __restrict__ row_start,
                                                    int nb, int N) {
  int t = threadIdx.x;
  int v = (t < nb) ? bsum[t] : 0;
  int inc = v;
#pragma unroll
  for (int o = 1; o < 64; o <<= 1) {
    int u = __shfl_up(inc, o);
    if ((t & 63) >= o) inc += u;
  }
  __shared__ int wt[4];
  if ((t & 63) == 63) wt[t >> 6] = inc;
  __syncthreads();
  int add = 0;
  for (int wv = 0; wv < (t >> 6); ++wv) add += wt[wv];
  inc += add;
  if (t < nb) boff[t] = inc - v;
  if (t == 255) row_start[N] = inc;
}

__global__ __launch_bounds__(256) void scanC_kernel(const int* __restrict__ deg,
                                                    const int* __restrict__ boff,
                                                    int* __restrict__ row_start,
                                                    int* __restrict__ cursor, int N) {
  int b = blockIdx.x, t = threadIdx.x;
  int base = b * 1024 + t * 4;
  int d[4];
  int s = 0;
#pragma unroll
  for (int j = 0; j < 4; ++j) {
    int i = base + j;
    d[j] = (i < N) ? deg[i] : 0;
    s += d[j];
  }
  int inc = s;
#pragma unroll
  for (int o = 1; o < 64; o <<= 1) {
    int u = __shfl_up(inc, o);
    if ((t & 63) >= o) inc += u;
  }
  __shared__ int wt[4];
  if ((t & 63) == 63) wt[t >> 6] = inc;
  __syncthreads();
  int add = boff[b];
  for (int wv = 0; wv < (t >> 6); ++wv) add += wt[wv];
  int off = add + inc - s;
#pragma unroll
  for (int j = 0; j < 4; ++j) {
    int i = base + j;
    if (i < N) {
      row_start[i] = off;
      cursor[i] = off;
      off += d[j];
    }
  }
}

__global__ __launch_bounds__(256) void scatter_kernel(
    const int* __restrict__ src, const int* __restrict__ dst, const int* __restrict__ et,
    int* __restrict__ cursor, int* __restrict__ es_src, int* __restrict__ es_dst,
    int* __restrict__ es_et, int* __restrict__ es_eid, int E) {
  int e = blockIdx.x * 256 + threadIdx.x;
  if (e >= E) return;
  int d = dst[e];
  int pos = atomicAdd(&cursor[d], 1);
  es_src[pos] = src[e];
  es_dst[pos] = d;
  es_et[pos] = et[e];
  es_eid[pos] = e;
}

// ---- bf16 split conversions ----
__global__ __launch_bounds__(256) void convx_kernel(const float* __restrict__ in,
                                                    unsigned short* __restrict__ hi,
                                                    unsigned short* __restrict__ lo,
                                                    int total8) {
  int i = blockIdx.x * 256 + threadIdx.x;
  if (i >= total8) return;
  const float4* p = (const float4*)in + (size_t)i * 2;
  float4 a = p[0], b = p[1];
  float v[8] = {a.x, a.y, a.z, a.w, b.x, b.y, b.z, b.w};
  bf16x8 hv, lv;
#pragma unroll
  for (int j = 0; j < 8; ++j) {
    unsigned short h, l;
    bf16split(v[j], h, l);
    hv[j] = (short)h; lv[j] = (short)l;
  }
  *(bf16x8*)(hi + (size_t)i * 8) = hv;
  *(bf16x8*)(lo + (size_t)i * 8) = lv;
}

__global__ void convw_kernel(const float* __restrict__ w,
                             unsigned short* __restrict__ hiT,
                             unsigned short* __restrict__ loT) {
  int f = blockIdx.x, r = blockIdx.y, o = threadIdx.x;
  float v = w[((size_t)r * 128 + f) * 128 + o];
  unsigned short h, l;
  bf16split(v, h, l);
  hiT[((size_t)r * 128 + o) * 128 + f] = h;
  loT[((size_t)r * 128 + o) * 128 + f] = l;
}

// ---- proj via MFMA, w staged in LDS fragment-major ----
// grid (R, ceil(N/128)), block 256 = 4 waves; wave handles 32 nodes x 128 o.
// LDS frag slot for (ot,kc,q,c): ((ot*4+kc)*4+q)*16 + c   (16 B per slot)
__global__ __launch_bounds__(256) void proj_mfma_kernel(
    const unsigned short* __restrict__ xhi, const unsigned short* __restrict__ xlo,
    const unsigned short* __restrict__ whiT, const unsigned short* __restrict__ wloT,
    float* __restrict__ xw, int N) {
  __shared__ bf16x8 wl_h[2048];  // 32 KB
  __shared__ bf16x8 wl_l[2048];  // 32 KB
  int r = blockIdx.x;
  int nb = blockIdx.y * 128;
  int t = threadIdx.x;
  const unsigned short* wh = whiT + (size_t)r * (128 * 128);
  const unsigned short* wl = wloT + (size_t)r * (128 * 128);

  // stage w into LDS (fragment-major): 8 slots/thread per array
#pragma unroll
  for (int j = 0; j < 8; ++j) {
    int i = j * 256 + t;
    int c = i & 15, q = (i >> 4) & 3, kc = (i >> 6) & 3, ot = i >> 8;
    int srco = (ot * 16 + c) * 128 + kc * 32 + q * 8;
    wl_h[i] = *(const bf16x8*)(wh + srco);
    wl_l[i] = *(const bf16x8*)(wl + srco);
  }
  __syncthreads();

  int wv = t >> 6;
  int lane = t & 63;
  int c = lane & 15, q = lane >> 4;
  int nodebase = nb + wv * 32;
  int n0 = nodebase + c;
  int n1 = nodebase + 16 + c;
  int n0c = n0 < N ? n0 : N - 1;
  int n1c = n1 < N ? n1 : N - 1;

  f32x4 acc[8][2];
#pragma unroll
  for (int ot = 0; ot < 8; ++ot)
#pragma unroll
    for (int nt = 0; nt < 2; ++nt) acc[ot][nt] = (f32x4){0.f, 0.f, 0.f, 0.f};

  // x fragments, double-buffered across kc
  bf16x8 xb[2][4];
  {
    int k0 = q * 8;
    xb[0][0] = *(const bf16x8*)(xhi + (size_t)n0c * 128 + k0);
    xb[0][1] = *(const bf16x8*)(xlo + (size_t)n0c * 128 + k0);
    xb[0][2] = *(const bf16x8*)(xhi + (size_t)n1c * 128 + k0);
    xb[0][3] = *(const bf16x8*)(xlo + (size_t)n1c * 128 + k0);
  }
#pragma unroll
  for (int kc = 0; kc < 4; ++kc) {
    if (kc < 3) {
      int k0 = (kc + 1) * 32 + q * 8;
      xb[(kc + 1) & 1][0] = *(const bf16x8*)(xhi + (size_t)n0c * 128 + k0);
      xb[(kc + 1) & 1][1] = *(const bf16x8*)(xlo + (size_t)n0c * 128 + k0);
      xb[(kc + 1) & 1][2] = *(const bf16x8*)(xhi + (size_t)n1c * 128 + k0);
      xb[(kc + 1) & 1][3] = *(const bf16x8*)(xlo + (size_t)n1c * 128 + k0);
    }
    bf16x8 b0h = xb[kc & 1][0], b0l = xb[kc & 1][1];
    bf16x8 b1h = xb[kc & 1][2], b1l = xb[kc & 1][3];
#pragma unroll
    for (int ot = 0; ot < 8; ++ot) {
      int fi = ((ot * 4 + kc) * 4 + q) * 16 + c;
      bf16x8 ah = wl_h[fi];
      bf16x8 al = wl_l[fi];
      acc[ot][0] = __builtin_amdgcn_mfma_f32_16x16x32_bf16(ah, b0h, acc[ot][0], 0, 0, 0);
      acc[ot][0] = __builtin_amdgcn_mfma_f32_16x16x32_bf16(ah, b0l, acc[ot][0], 0, 0, 0);
      acc[ot][0] = __builtin_amdgcn_mfma_f32_16x16x32_bf16(al, b0h, acc[ot][0], 0, 0, 0);
      acc[ot][1] = __builtin_amdgcn_mfma_f32_16x16x32_bf16(ah, b1h, acc[ot][1], 0, 0, 0);
      acc[ot][1] = __builtin_amdgcn_mfma_f32_16x16x32_bf16(ah, b1l, acc[ot][1], 0, 0, 0);
      acc[ot][1] = __builtin_amdgcn_mfma_f32_16x16x32_bf16(al, b1h, acc[ot][1], 0, 0, 0);
    }
  }

  // D: col=lane&15 -> node within tile; row=q*4+reg -> o within tile
#pragma unroll
  for (int nt = 0; nt < 2; ++nt) {
    int n = nodebase + nt * 16 + c;
    if (n < N) {
      float* base = xw + ((size_t)r * N + n) * 128 + q * 4;
#pragma unroll
      for (int ot = 0; ot < 8; ++ot)
        *(f32x4*)(base + ot * 16) = acc[ot][nt];
    }
  }
}

// qn[row,h], kn[row,h] for row in [0, R*N): 64 rows/block, 4 threads/row
__global__ __launch_bounds__(256) void qk_kernel(const float* __restrict__ xw,
                                                 const float* __restrict__ q,
                                                 const float* __restrict__ k,
                                                 float* __restrict__ qn,
                                                 float* __restrict__ kn, int total) {
  __shared__ float sx[64 * 132];
  __shared__ float sq[512];
  __shared__ float sk[512];
  int rb = blockIdx.x * 64;
  int t = threadIdx.x;
  if (t < 128) ((float4*)sq)[t] = ((const float4*)q)[t];
  else if (t < 256) ((float4*)sk)[t - 128] = ((const float4*)k)[t - 128];
  int nrow = total - rb; if (nrow > 64) nrow = 64;
  const float4* s4 = (const float4*)(xw + (size_t)rb * 128);
  for (int i = t; i < nrow * 32; i += 256) {
    ((float4*)sx)[(i >> 5) * 33 + (i & 31)] = s4[i];
  }
  __syncthreads();
  int rl = t >> 2, l = t & 3;
  float aq[4] = {0, 0, 0, 0}, ak[4] = {0, 0, 0, 0};
  for (int i = 0; i < 32; ++i) {
    int o = l + 4 * i;
    float xv = sx[rl * 132 + o];
#pragma unroll
    for (int h = 0; h < 4; ++h) {
      aq[h] += xv * sq[o * 4 + h];
      ak[h] += xv * sk[o * 4 + h];
    }
  }
#pragma unroll
  for (int h = 0; h < 4; ++h) {
    aq[h] += __shfl_xor(aq[h], 1); aq[h] += __shfl_xor(aq[h], 2);
    ak[h] += __shfl_xor(ak[h], 1); ak[h] += __shfl_xor(ak[h], 2);
  }
  int row = rb + rl;
  if (l == 0 && row < total) {
    *(float4*)(qn + (size_t)row * 4) = make_float4(aq[0], aq[1], aq[2], aq[3]);
    *(float4*)(kn + (size_t)row * 4) = make_float4(ak[0], ak[1], ak[2], ak[3]);
  }
}

// ek[e,h] = sum_{f<16} ea[e,f]*lee[f,h]
__global__ __launch_bounds__(256) void ek_kernel(const float* __restrict__ ea,
                                                 const float* __restrict__ lee,
                                                 float* __restrict__ ek, int E) {
  __shared__ float sl[64];
  if (threadIdx.x < 64) sl[threadIdx.x] = lee[threadIdx.x];
  __syncthreads();
  int e = blockIdx.x * 256 + threadIdx.x;
  if (e >= E) return;
  const float4* a4 = (const float4*)(ea + (size_t)e * 16);
  float acc[4] = {0, 0, 0, 0};
#pragma unroll
  for (int i = 0; i < 4; ++i) {
    float4 v = a4[i];
    int f = i * 4;
#pragma unroll
    for (int h = 0; h < 4; ++h) {
      acc[h] += v.x * sl[f * 4 + h] + v.y * sl[(f + 1) * 4 + h] +
                v.z * sl[(f + 2) * 4 + h] + v.w * sl[(f + 3) * 4 + h];
    }
  }
  *(float4*)(ek + (size_t)e * 4) = make_float4(acc[0], acc[1], acc[2], acc[3]);
}

// alpha in dst-sorted order
__global__ __launch_bounds__(256) void alpha_kernel(
    const int* __restrict__ es_src, const int* __restrict__ es_dst,
    const int* __restrict__ es_et, const int* __restrict__ es_eid,
    const float* __restrict__ qn, const float* __restrict__ kn,
    const float* __restrict__ ek, float* __restrict__ alpha_s, int E, int N) {
  int i = blockIdx.x * 256 + threadIdx.x;
  if (i >= E) return;
  int s = es_src[i], d = es_dst[i], et = es_et[i], e = es_eid[i];
  float4 qv = *(const float4*)(qn + ((size_t)et * N + d) * 4);
  float4 kv = *(const float4*)(kn + ((size_t)et * N + s) * 4);
  float4 ev = *(const float4*)(ek + (size_t)e * 4);
  float a0 = qv.x + kv.x + ev.x, a1 = qv.y + kv.y + ev.y;
  float a2 = qv.z + kv.z + ev.z, a3 = qv.w + kv.w + ev.w;
  a0 = a0 > 0.f ? a0 : NEG_SLOPE * a0;
  a1 = a1 > 0.f ? a1 : NEG_SLOPE * a1;
  a2 = a2 > 0.f ? a2 : NEG_SLOPE * a2;
  a3 = a3 > 0.f ? a3 : NEG_SLOPE * a3;
  *(float4*)(alpha_s + (size_t)i * 4) = make_float4(a0, a1, a2, a3);
}

// fused softmax + gather-aggregate + epilogue. One wave per dst node.
__global__ __launch_bounds__(256) void agg_kernel(
    const int* __restrict__ es_src, const int* __restrict__ es_et,
    const int* __restrict__ row_start, float* __restrict__ alpha_s,
    const float* __restrict__ xw, const float* __restrict__ bias,
    float* __restrict__ out, int N, int concat) {
  int d = blockIdx.x * 4 + (threadIdx.x >> 6);
  if (d >= N) return;
  int lane = threadIdx.x & 63;
  int rs = row_start[d], re = row_start[d + 1];

  float4 mx = make_float4(-1e30f, -1e30f, -1e30f, -1e30f);
  for (int i = rs + lane; i < re; i += 64) {
    float4 a = ((const float4*)alpha_s)[i];
    mx.x = fmaxf(mx.x, a.x); mx.y = fmaxf(mx.y, a.y);
    mx.z = fmaxf(mx.z, a.z); mx.w = fmaxf(mx.w, a.w);
  }
#pragma unroll
  for (int o = 32; o >= 1; o >>= 1) {
    mx.x = fmaxf(mx.x, __shfl_xor(mx.x, o));
    mx.y = fmaxf(mx.y, __shfl_xor(mx.y, o));
    mx.z = fmaxf(mx.z, __shfl_xor(mx.z, o));
    mx.w = fmaxf(mx.w, __shfl_xor(mx.w, o));
  }
  float4 sm = make_float4(0.f, 0.f, 0.f, 0.f);
  for (int i = rs + lane; i < re; i += 64) {
    float4 a = ((float4*)alpha_s)[i];
    a.x = __expf(a.x - mx.x); a.y = __expf(a.y - mx.y);
    a.z = __expf(a.z - mx.z); a.w = __expf(a.w - mx.w);
    ((float4*)alpha_s)[i] = a;
    sm.x += a.x; sm.y += a.y; sm.z += a.z; sm.w += a.w;
  }
#pragma unroll
  for (int o = 32; o >= 1; o >>= 1) {
    sm.x += __shfl_xor(sm.x, o); sm.y += __shfl_xor(sm.y, o);
    sm.z += __shfl_xor(sm.z, o); sm.w += __shfl_xor(sm.w, o);
  }

  int half = lane >> 5;
  int cl = lane & 31;
  int h = cl >> 3;
  float smh = (h == 0) ? sm.x : (h == 1) ? sm.y : (h == 2) ? sm.z : sm.w;
  float rden = 1.f / (smh + SOFT_EPS);

  float4 acc = make_float4(0.f, 0.f, 0.f, 0.f);
  int base = rs;
  for (; base + 4 <= re; base += 4) {
    int e0 = base + half;
    int e1 = base + 2 + half;
    int s0 = es_src[e0], t0 = es_et[e0];
    int s1 = es_src[e1], t1 = es_et[e1];
    float w0 = alpha_s[(size_t)e0 * 4 + h];
    float w1 = alpha_s[(size_t)e1 * 4 + h];
    float4 x0 = *(const float4*)(xw + ((size_t)t0 * N + s0) * 128 + cl * 4);
    float4 x1 = *(const float4*)(xw + ((size_t)t1 * N + s1) * 128 + cl * 4);
    acc.x += w0 * x0.x; acc.y += w0 * x0.y; acc.z += w0 * x0.z; acc.w += w0 * x0.w;
    acc.x += w1 * x1.x; acc.y += w1 * x1.y; acc.z += w1 * x1.z; acc.w += w1 * x1.w;
  }
  for (; base < re; base += 2) {
    int e = base + half;
    if (e < re) {
      int s = es_src[e], t = es_et[e];
      float w = alpha_s[(size_t)e * 4 + h];
      float4 xv = *(const float4*)(xw + ((size_t)t * N + s) * 128 + cl * 4);
      acc.x += w * xv.x; acc.y += w * xv.y; acc.z += w * xv.z; acc.w += w * xv.w;
    }
  }
  acc.x *= rden; acc.y *= rden; acc.z *= rden; acc.w *= rden;
  acc.x += __shfl_xor(acc.x, 32); acc.y += __shfl_xor(acc.y, 32);
  acc.z += __shfl_xor(acc.z, 32); acc.w += __shfl_xor(acc.w, 32);

  if (concat) {
    if (half == 0) {
      float4 bv = ((const float4*)bias)[cl];
      float4 v = make_float4(acc.x + bv.x, acc.y + bv.y, acc.z + bv.z, acc.w + bv.w);
      v.x = v.x > 0.f ? v.x : 0.f;
      v.y = v.y > 0.f ? v.y : 0.f;
      v.z = v.z > 0.f ? v.z : 0.f;
      v.w = v.w > 0.f ? v.w : 0.f;
      ((float4*)(out + (size_t)d * 128))[cl] = v;
    }
  } else {
    acc.x += __shfl_xor(acc.x, 8);  acc.y += __shfl_xor(acc.y, 8);
    acc.z += __shfl_xor(acc.z, 8);  acc.w += __shfl_xor(acc.w, 8);
    acc.x += __shfl_xor(acc.x, 16); acc.y += __shfl_xor(acc.y, 16);
    acc.z += __shfl_xor(acc.z, 16); acc.w += __shfl_xor(acc.w, 16);
    if (lane < 8) {
      float4 bv = ((const float4*)bias)[lane];
      float4 v = make_float4(0.25f * acc.x + bv.x, 0.25f * acc.y + bv.y,
                             0.25f * acc.z + bv.z, 0.25f * acc.w + bv.w);
      ((float4*)(out + (size_t)d * 32))[lane] = v;
    }
  }
}

extern "C" void kernel_launch(void* const* d_in, const int* in_sizes, int n_in,
                              void* d_out, int out_size, void* d_ws, size_t ws_size,
                              hipStream_t stream) {
  const float* x   = (const float*)d_in[0];
  const int*   ei  = (const int*)d_in[1];
  const float* ea  = (const float*)d_in[2];
  const int*   etp = (const int*)d_in[3];
  const float* w1  = (const float*)d_in[4];
  const float* q1  = (const float*)d_in[5];
  const float* k1  = (const float*)d_in[6];
  const float* e1  = (const float*)d_in[7];
  const float* le1 = (const float*)d_in[8];
  const float* b1  = (const float*)d_in[9];
  const float* w3  = (const float*)d_in[10];
  const float* q3  = (const float*)d_in[11];
  const float* k3  = (const float*)d_in[12];
  const float* e3  = (const float*)d_in[13];
  const float* le3 = (const float*)d_in[14];
  const float* b3  = (const float*)d_in[15];
  const int N = in_sizes[0] / 128;
  const int E = in_sizes[3];
  const int* srcp = ei;
  const int* dstp = ei + E;

  float* ws   = (float*)d_ws;
  float* xw   = ws;                                  // 4*N*128
  float* qn   = xw + (size_t)4 * N * 128;            // 4*N*4
  float* kn   = qn + (size_t)4 * N * 4;              // 4*N*4
  float* ekb  = kn + (size_t)4 * N * 4;              // E*4
  float* alph = ekb + (size_t)E * 4;                 // E*4
  float* hbuf = alph + (size_t)E * 4;                // N*128
  float* leeb = hbuf + (size_t)N * 128;              // 128
  int* deg      = (int*)(leeb + 128);                // N
  int* rowst    = deg + N;                           // N+1
  int* cursor   = rowst + N + 1;                     // N
  int* es_src   = cursor + N;                        // E
  int* es_dst   = es_src + E;                        // E
  int* es_et    = es_dst + E;                        // E
  int* es_eid   = es_et + E;                         // E
  int* bsum     = es_eid + E;                        // 256
  int* boff     = bsum + 256;                        // 256
  uintptr_t pa = (uintptr_t)(boff + 256);
  pa = (pa + 255) & ~(uintptr_t)255;
  unsigned short* xhi  = (unsigned short*)pa;        // N*128
  unsigned short* xlo  = xhi + (size_t)N * 128;      // N*128
  unsigned short* whiT = xlo + (size_t)N * 128;      // 4*128*128
  unsigned short* wloT = whiT + 4 * 128 * 128;       // 4*128*128
  (void)ws_size; (void)n_in; (void)out_size;

  int qkb  = (4 * N + 63) / 64;
  int eb   = (E + 255) / 256;
  int nb4  = (N + 3) / 4;
  int nbs  = (N + 1023) / 1024;
  int pgy  = (N + 127) / 128;
  int cxb  = (N * 128 / 8 + 255) / 256;

  hipMemsetAsync(deg, 0, (size_t)N * sizeof(int), stream);
  hist_kernel<<<eb, 256, 0, stream>>>(dstp, deg, E);
  scanA_kernel<<<nbs, 256, 0, stream>>>(deg, bsum, N);
  scanB_kernel<<<1, 256, 0, stream>>>(bsum, boff, rowst, nbs, N);
  scanC_kernel<<<nbs, 256, 0, stream>>>(deg, boff, rowst, cursor, N);
  scatter_kernel<<<eb, 256, 0, stream>>>(srcp, dstp, etp, cursor,
                                         es_src, es_dst, es_et, es_eid, E);
  lee_kernel<<<1, 128, 0, stream>>>(le1, e1, le3, e3, leeb);

  for (int layer = 0; layer < 2; ++layer) {
    const float* xin = layer ? hbuf : x;
    const float* w   = layer ? w3 : w1;
    const float* q   = layer ? q3 : q1;
    const float* k   = layer ? k3 : k1;
    const float* leep = leeb + (layer ? 64 : 0);
    const float* bias = layer ? b3 : b1;
    float* outp = layer ? (float*)d_out : hbuf;

    convx_kernel<<<cxb, 256, 0, stream>>>(xin, xhi, xlo, N * 128 / 8);
    convw_kernel<<<dim3(128, 4), 128, 0, stream>>>(w, whiT, wloT);
    proj_mfma_kernel<<<dim3(4, pgy), 256, 0, stream>>>(xhi, xlo, whiT, wloT, xw, N);
    qk_kernel<<<qkb, 256, 0, stream>>>(xw, q, k, qn, kn, 4 * N);
    ek_kernel<<<eb, 256, 0, stream>>>(ea, leep, ekb, E);
    alpha_kernel<<<eb, 256, 0, stream>>>(es_src, es_dst, es_et, es_eid,
                                         qn, kn, ekb, alph, E, N);
    agg_kernel<<<nb4, 256, 0, stream>>>(es_src, es_et, rowst, alph, xw,
                                        bias, outp, N, layer == 0 ? 1 : 0);
  }
}

// Round 8
// 581.488 us; speedup vs baseline: 1.2878x; 1.0501x over previous
//
#include <hip/hip_runtime.h>

// RGATNetwork: 2x RGATConv (R=4, H=4, C=32, HC=128, F_E=16) on N=50k nodes, E=800k edges.
// R8: scatter write-amplification fix — per-edge fields packed into one int4
// array es[pos]={src,dst,et,eid}: 1x16B scattered store (was 4x4B into 4 arrays,
// 130 MB of dirtied lines for 12.8 MB payload). alpha/agg read the packed int4.
// Rest unchanged from R7 (LDS-staged split-bf16 MFMA proj, CSR gather agg).

#define NEG_SLOPE 0.2f
#define SOFT_EPS 1e-16f

typedef __attribute__((ext_vector_type(8))) short bf16x8;
typedef __attribute__((ext_vector_type(4))) float f32x4;

__device__ __forceinline__ void bf16split(float f, unsigned short& h, unsigned short& l) {
  unsigned u = __float_as_uint(f);
  unsigned r = u + 0x7FFFu + ((u >> 16) & 1u);
  h = (unsigned short)(r >> 16);
  float fh = __uint_as_float(((unsigned)h) << 16);
  float d = f - fh;
  unsigned u2 = __float_as_uint(d);
  unsigned r2 = u2 + 0x7FFFu + ((u2 >> 16) & 1u);
  l = (unsigned short)(r2 >> 16);
}

// lee[f,h] = sum_o le[f,o]*e[o,h]  for both layers (t<64: layer1, t>=64: layer3)
__global__ void lee_kernel(const float* __restrict__ le1, const float* __restrict__ e1,
                           const float* __restrict__ le3, const float* __restrict__ e3,
                           float* __restrict__ lee) {
  int t = threadIdx.x;
  const float* le = (t < 64) ? le1 : le3;
  const float* ee = (t < 64) ? e1 : e3;
  int u = t & 63, f = u >> 2, h = u & 3;
  float acc = 0.f;
  for (int o = 0; o < 128; ++o) acc += le[f * 128 + o] * ee[o * 4 + h];
  lee[t] = acc;
}

// ---- CSR build ----
__global__ __launch_bounds__(256) void hist_kernel(const int* __restrict__ dst,
                                                   int* __restrict__ deg, int E) {
  int e = blockIdx.x * 256 + threadIdx.x;
  if (e < E) atomicAdd(&deg[dst[e]], 1);
}

__global__ __launch_bounds__(256) void scanA_kernel(const int* __restrict__ deg,
                                                    int* __restrict__ bsum, int N) {
  int b = blockIdx.x, t = threadIdx.x;
  int base = b * 1024 + t * 4;
  int s = 0;
#pragma unroll
  for (int j = 0; j < 4; ++j) {
    int i = base + j;
    if (i < N) s += deg[i];
  }
#pragma unroll
  for (int o = 1; o < 64; o <<= 1) s += __shfl_xor(s, o);
  __shared__ int wsum[4];
  if ((t & 63) == 0) wsum[t >> 6] = s;
  __syncthreads();
  if (t == 0) bsum[b] = wsum[0] + wsum[1] + wsum[2] + wsum[3];
}

__global__ __launch_bounds__(256) void scanB_kernel(const int* __restrict__ bsum,
                                                    int* __restrict__ boff,
                                                    int* __restrict__ row_start,
                                                    int nb, int N) {
  int t = threadIdx.x;
  int v = (t < nb) ? bsum[t] : 0;
  int inc = v;
#pragma unroll
  for (int o = 1; o < 64; o <<= 1) {
    int u = __shfl_up(inc, o);
    if ((t & 63) >= o) inc += u;
  }
  __shared__ int wt[4];
  if ((t & 63) == 63) wt[t >> 6] = inc;
  __syncthreads();
  int add = 0;
  for (int wv = 0; wv < (t >> 6); ++wv) add += wt[wv];
  inc += add;
  if (t < nb) boff[t] = inc - v;
  if (t == 255) row_start[N] = inc;
}

__global__ __launch_bounds__(256) void scanC_kernel(const int* __restrict__ deg,
                                                    const int* __restrict__ boff,
                                                    int* __restrict__ row_start,
                                                    int* __restrict__ cursor, int N) {
  int b = blockIdx.x, t = threadIdx.x;
  int base = b * 1024 + t * 4;
  int d[4];
  int s = 0;
#pragma unroll
  for (int j = 0; j < 4; ++j) {
    int i = base + j;
    d[j] = (i < N) ? deg[i] : 0;
    s += d[j];
  }
  int inc = s;
#pragma unroll
  for (int o = 1; o < 64; o <<= 1) {
    int u = __shfl_up(inc, o);
    if ((t & 63) >= o) inc += u;
  }
  __shared__ int wt[4];
  if ((t & 63) == 63) wt[t >> 6] = inc;
  __syncthreads();
  int add = boff[b];
  for (int wv = 0; wv < (t >> 6); ++wv) add += wt[wv];
  int off = add + inc - s;
#pragma unroll
  for (int j = 0; j < 4; ++j) {
    int i = base + j;
    if (i < N) {
      row_start[i] = off;
      cursor[i] = off;
      off += d[j];
    }
  }
}

// packed scatter: es[pos] = {src, dst, et, eid} (one 16B store per edge)
__global__ __launch_bounds__(256) void scatter_kernel(
    const int* __restrict__ src, const int* __restrict__ dst, const int* __restrict__ et,
    int* __restrict__ cursor, int4* __restrict__ es, int E) {
  int e = blockIdx.x * 256 + threadIdx.x;
  if (e >= E) return;
  int d = dst[e];
  int pos = atomicAdd(&cursor[d], 1);
  es[pos] = make_int4(src[e], d, et[e], e);
}

// ---- bf16 split conversions ----
__global__ __launch_bounds__(256) void convx_kernel(const float* __restrict__ in,
                                                    unsigned short* __restrict__ hi,
                                                    unsigned short* __restrict__ lo,
                                                    int total8) {
  int i = blockIdx.x * 256 + threadIdx.x;
  if (i >= total8) return;
  const float4* p = (const float4*)in + (size_t)i * 2;
  float4 a = p[0], b = p[1];
  float v[8] = {a.x, a.y, a.z, a.w, b.x, b.y, b.z, b.w};
  bf16x8 hv, lv;
#pragma unroll
  for (int j = 0; j < 8; ++j) {
    unsigned short h, l;
    bf16split(v[j], h, l);
    hv[j] = (short)h; lv[j] = (short)l;
  }
  *(bf16x8*)(hi + (size_t)i * 8) = hv;
  *(bf16x8*)(lo + (size_t)i * 8) = lv;
}

__global__ void convw_kernel(const float* __restrict__ w,
                             unsigned short* __restrict__ hiT,
                             unsigned short* __restrict__ loT) {
  int f = blockIdx.x, r = blockIdx.y, o = threadIdx.x;
  float v = w[((size_t)r * 128 + f) * 128 + o];
  unsigned short h, l;
  bf16split(v, h, l);
  hiT[((size_t)r * 128 + o) * 128 + f] = h;
  loT[((size_t)r * 128 + o) * 128 + f] = l;
}

// ---- proj via MFMA, w staged in LDS fragment-major ----
__global__ __launch_bounds__(256) void proj_mfma_kernel(
    const unsigned short* __restrict__ xhi, const unsigned short* __restrict__ xlo,
    const unsigned short* __restrict__ whiT, const unsigned short* __restrict__ wloT,
    float* __restrict__ xw, int N) {
  __shared__ bf16x8 wl_h[2048];  // 32 KB
  __shared__ bf16x8 wl_l[2048];  // 32 KB
  int r = blockIdx.x;
  int nb = blockIdx.y * 128;
  int t = threadIdx.x;
  const unsigned short* wh = whiT + (size_t)r * (128 * 128);
  const unsigned short* wl = wloT + (size_t)r * (128 * 128);

#pragma unroll
  for (int j = 0; j < 8; ++j) {
    int i = j * 256 + t;
    int c = i & 15, q = (i >> 4) & 3, kc = (i >> 6) & 3, ot = i >> 8;
    int srco = (ot * 16 + c) * 128 + kc * 32 + q * 8;
    wl_h[i] = *(const bf16x8*)(wh + srco);
    wl_l[i] = *(const bf16x8*)(wl + srco);
  }
  __syncthreads();

  int wv = t >> 6;
  int lane = t & 63;
  int c = lane & 15, q = lane >> 4;
  int nodebase = nb + wv * 32;
  int n0 = nodebase + c;
  int n1 = nodebase + 16 + c;
  int n0c = n0 < N ? n0 : N - 1;
  int n1c = n1 < N ? n1 : N - 1;

  f32x4 acc[8][2];
#pragma unroll
  for (int ot = 0; ot < 8; ++ot)
#pragma unroll
    for (int nt = 0; nt < 2; ++nt) acc[ot][nt] = (f32x4){0.f, 0.f, 0.f, 0.f};

  bf16x8 xb[2][4];
  {
    int k0 = q * 8;
    xb[0][0] = *(const bf16x8*)(xhi + (size_t)n0c * 128 + k0);
    xb[0][1] = *(const bf16x8*)(xlo + (size_t)n0c * 128 + k0);
    xb[0][2] = *(const bf16x8*)(xhi + (size_t)n1c * 128 + k0);
    xb[0][3] = *(const bf16x8*)(xlo + (size_t)n1c * 128 + k0);
  }
#pragma unroll
  for (int kc = 0; kc < 4; ++kc) {
    if (kc < 3) {
      int k0 = (kc + 1) * 32 + q * 8;
      xb[(kc + 1) & 1][0] = *(const bf16x8*)(xhi + (size_t)n0c * 128 + k0);
      xb[(kc + 1) & 1][1] = *(const bf16x8*)(xlo + (size_t)n0c * 128 + k0);
      xb[(kc + 1) & 1][2] = *(const bf16x8*)(xhi + (size_t)n1c * 128 + k0);
      xb[(kc + 1) & 1][3] = *(const bf16x8*)(xlo + (size_t)n1c * 128 + k0);
    }
    bf16x8 b0h = xb[kc & 1][0], b0l = xb[kc & 1][1];
    bf16x8 b1h = xb[kc & 1][2], b1l = xb[kc & 1][3];
#pragma unroll
    for (int ot = 0; ot < 8; ++ot) {
      int fi = ((ot * 4 + kc) * 4 + q) * 16 + c;
      bf16x8 ah = wl_h[fi];
      bf16x8 al = wl_l[fi];
      acc[ot][0] = __builtin_amdgcn_mfma_f32_16x16x32_bf16(ah, b0h, acc[ot][0], 0, 0, 0);
      acc[ot][0] = __builtin_amdgcn_mfma_f32_16x16x32_bf16(ah, b0l, acc[ot][0], 0, 0, 0);
      acc[ot][0] = __builtin_amdgcn_mfma_f32_16x16x32_bf16(al, b0h, acc[ot][0], 0, 0, 0);
      acc[ot][1] = __builtin_amdgcn_mfma_f32_16x16x32_bf16(ah, b1h, acc[ot][1], 0, 0, 0);
      acc[ot][1] = __builtin_amdgcn_mfma_f32_16x16x32_bf16(ah, b1l, acc[ot][1], 0, 0, 0);
      acc[ot][1] = __builtin_amdgcn_mfma_f32_16x16x32_bf16(al, b1h, acc[ot][1], 0, 0, 0);
    }
  }

#pragma unroll
  for (int nt = 0; nt < 2; ++nt) {
    int n = nodebase + nt * 16 + c;
    if (n < N) {
      float* base = xw + ((size_t)r * N + n) * 128 + q * 4;
#pragma unroll
      for (int ot = 0; ot < 8; ++ot)
        *(f32x4*)(base + ot * 16) = acc[ot][nt];
    }
  }
}

// qn[row,h], kn[row,h] for row in [0, R*N): 64 rows/block, 4 threads/row
__global__ __launch_bounds__(256) void qk_kernel(const float* __restrict__ xw,
                                                 const float* __restrict__ q,
                                                 const float* __restrict__ k,
                                                 float* __restrict__ qn,
                                                 float* __restrict__ kn, int total) {
  __shared__ float sx[64 * 132];
  __shared__ float sq[512];
  __shared__ float sk[512];
  int rb = blockIdx.x * 64;
  int t = threadIdx.x;
  if (t < 128) ((float4*)sq)[t] = ((const float4*)q)[t];
  else if (t < 256) ((float4*)sk)[t - 128] = ((const float4*)k)[t - 128];
  int nrow = total - rb; if (nrow > 64) nrow = 64;
  const float4* s4 = (const float4*)(xw + (size_t)rb * 128);
  for (int i = t; i < nrow * 32; i += 256) {
    ((float4*)sx)[(i >> 5) * 33 + (i & 31)] = s4[i];
  }
  __syncthreads();
  int rl = t >> 2, l = t & 3;
  float aq[4] = {0, 0, 0, 0}, ak[4] = {0, 0, 0, 0};
  for (int i = 0; i < 32; ++i) {
    int o = l + 4 * i;
    float xv = sx[rl * 132 + o];
#pragma unroll
    for (int h = 0; h < 4; ++h) {
      aq[h] += xv * sq[o * 4 + h];
      ak[h] += xv * sk[o * 4 + h];
    }
  }
#pragma unroll
  for (int h = 0; h < 4; ++h) {
    aq[h] += __shfl_xor(aq[h], 1); aq[h] += __shfl_xor(aq[h], 2);
    ak[h] += __shfl_xor(ak[h], 1); ak[h] += __shfl_xor(ak[h], 2);
  }
  int row = rb + rl;
  if (l == 0 && row < total) {
    *(float4*)(qn + (size_t)row * 4) = make_float4(aq[0], aq[1], aq[2], aq[3]);
    *(float4*)(kn + (size_t)row * 4) = make_float4(ak[0], ak[1], ak[2], ak[3]);
  }
}

// ek[e,h] = sum_{f<16} ea[e,f]*lee[f,h]
__global__ __launch_bounds__(256) void ek_kernel(const float* __restrict__ ea,
                                                 const float* __restrict__ lee,
                                                 float* __restrict__ ek, int E) {
  __shared__ float sl[64];
  if (threadIdx.x < 64) sl[threadIdx.x] = lee[threadIdx.x];
  __syncthreads();
  int e = blockIdx.x * 256 + threadIdx.x;
  if (e >= E) return;
  const float4* a4 = (const float4*)(ea + (size_t)e * 16);
  float acc[4] = {0, 0, 0, 0};
#pragma unroll
  for (int i = 0; i < 4; ++i) {
    float4 v = a4[i];
    int f = i * 4;
#pragma unroll
    for (int h = 0; h < 4; ++h) {
      acc[h] += v.x * sl[f * 4 + h] + v.y * sl[(f + 1) * 4 + h] +
                v.z * sl[(f + 2) * 4 + h] + v.w * sl[(f + 3) * 4 + h];
    }
  }
  *(float4*)(ek + (size_t)e * 4) = make_float4(acc[0], acc[1], acc[2], acc[3]);
}

// alpha in dst-sorted order; reads packed es
__global__ __launch_bounds__(256) void alpha_kernel(
    const int4* __restrict__ es, const float* __restrict__ qn,
    const float* __restrict__ kn, const float* __restrict__ ek,
    float* __restrict__ alpha_s, int E, int N) {
  int i = blockIdx.x * 256 + threadIdx.x;
  if (i >= E) return;
  int4 v = es[i];
  int s = v.x, d = v.y, et = v.z, e = v.w;
  float4 qv = *(const float4*)(qn + ((size_t)et * N + d) * 4);
  float4 kv = *(const float4*)(kn + ((size_t)et * N + s) * 4);
  float4 ev = *(const float4*)(ek + (size_t)e * 4);
  float a0 = qv.x + kv.x + ev.x, a1 = qv.y + kv.y + ev.y;
  float a2 = qv.z + kv.z + ev.z, a3 = qv.w + kv.w + ev.w;
  a0 = a0 > 0.f ? a0 : NEG_SLOPE * a0;
  a1 = a1 > 0.f ? a1 : NEG_SLOPE * a1;
  a2 = a2 > 0.f ? a2 : NEG_SLOPE * a2;
  a3 = a3 > 0.f ? a3 : NEG_SLOPE * a3;
  *(float4*)(alpha_s + (size_t)i * 4) = make_float4(a0, a1, a2, a3);
}

// fused softmax + gather-aggregate + epilogue. One wave per dst node.
__global__ __launch_bounds__(256) void agg_kernel(
    const int4* __restrict__ es, const int* __restrict__ row_start,
    float* __restrict__ alpha_s, const float* __restrict__ xw,
    const float* __restrict__ bias, float* __restrict__ out, int N, int concat) {
  int d = blockIdx.x * 4 + (threadIdx.x >> 6);
  if (d >= N) return;
  int lane = threadIdx.x & 63;
  int rs = row_start[d], re = row_start[d + 1];

  float4 mx = make_float4(-1e30f, -1e30f, -1e30f, -1e30f);
  for (int i = rs + lane; i < re; i += 64) {
    float4 a = ((const float4*)alpha_s)[i];
    mx.x = fmaxf(mx.x, a.x); mx.y = fmaxf(mx.y, a.y);
    mx.z = fmaxf(mx.z, a.z); mx.w = fmaxf(mx.w, a.w);
  }
#pragma unroll
  for (int o = 32; o >= 1; o >>= 1) {
    mx.x = fmaxf(mx.x, __shfl_xor(mx.x, o));
    mx.y = fmaxf(mx.y, __shfl_xor(mx.y, o));
    mx.z = fmaxf(mx.z, __shfl_xor(mx.z, o));
    mx.w = fmaxf(mx.w, __shfl_xor(mx.w, o));
  }
  float4 sm = make_float4(0.f, 0.f, 0.f, 0.f);
  for (int i = rs + lane; i < re; i += 64) {
    float4 a = ((float4*)alpha_s)[i];
    a.x = __expf(a.x - mx.x); a.y = __expf(a.y - mx.y);
    a.z = __expf(a.z - mx.z); a.w = __expf(a.w - mx.w);
    ((float4*)alpha_s)[i] = a;
    sm.x += a.x; sm.y += a.y; sm.z += a.z; sm.w += a.w;
  }
#pragma unroll
  for (int o = 32; o >= 1; o >>= 1) {
    sm.x += __shfl_xor(sm.x, o); sm.y += __shfl_xor(sm.y, o);
    sm.z += __shfl_xor(sm.z, o); sm.w += __shfl_xor(sm.w, o);
  }

  int half = lane >> 5;
  int cl = lane & 31;
  int h = cl >> 3;
  float smh = (h == 0) ? sm.x : (h == 1) ? sm.y : (h == 2) ? sm.z : sm.w;
  float rden = 1.f / (smh + SOFT_EPS);

  float4 acc = make_float4(0.f, 0.f, 0.f, 0.f);
  int base = rs;
  for (; base + 4 <= re; base += 4) {
    int e0 = base + half;
    int e1 = base + 2 + half;
    int4 a0 = es[e0];
    int4 a1 = es[e1];
    float w0 = alpha_s[(size_t)e0 * 4 + h];
    float w1 = alpha_s[(size_t)e1 * 4 + h];
    float4 x0 = *(const float4*)(xw + ((size_t)a0.z * N + a0.x) * 128 + cl * 4);
    float4 x1 = *(const float4*)(xw + ((size_t)a1.z * N + a1.x) * 128 + cl * 4);
    acc.x += w0 * x0.x; acc.y += w0 * x0.y; acc.z += w0 * x0.z; acc.w += w0 * x0.w;
    acc.x += w1 * x1.x; acc.y += w1 * x1.y; acc.z += w1 * x1.z; acc.w += w1 * x1.w;
  }
  for (; base < re; base += 2) {
    int e = base + half;
    if (e < re) {
      int4 a = es[e];
      float w = alpha_s[(size_t)e * 4 + h];
      float4 xv = *(const float4*)(xw + ((size_t)a.z * N + a.x) * 128 + cl * 4);
      acc.x += w * xv.x; acc.y += w * xv.y; acc.z += w * xv.z; acc.w += w * xv.w;
    }
  }
  acc.x *= rden; acc.y *= rden; acc.z *= rden; acc.w *= rden;
  acc.x += __shfl_xor(acc.x, 32); acc.y += __shfl_xor(acc.y, 32);
  acc.z += __shfl_xor(acc.z, 32); acc.w += __shfl_xor(acc.w, 32);

  if (concat) {
    if (half == 0) {
      float4 bv = ((const float4*)bias)[cl];
      float4 v = make_float4(acc.x + bv.x, acc.y + bv.y, acc.z + bv.z, acc.w + bv.w);
      v.x = v.x > 0.f ? v.x : 0.f;
      v.y = v.y > 0.f ? v.y : 0.f;
      v.z = v.z > 0.f ? v.z : 0.f;
      v.w = v.w > 0.f ? v.w : 0.f;
      ((float4*)(out + (size_t)d * 128))[cl] = v;
    }
  } else {
    acc.x += __shfl_xor(acc.x, 8);  acc.y += __shfl_xor(acc.y, 8);
    acc.z += __shfl_xor(acc.z, 8);  acc.w += __shfl_xor(acc.w, 8);
    acc.x += __shfl_xor(acc.x, 16); acc.y += __shfl_xor(acc.y, 16);
    acc.z += __shfl_xor(acc.z, 16); acc.w += __shfl_xor(acc.w, 16);
    if (lane < 8) {
      float4 bv = ((const float4*)bias)[lane];
      float4 v = make_float4(0.25f * acc.x + bv.x, 0.25f * acc.y + bv.y,
                             0.25f * acc.z + bv.z, 0.25f * acc.w + bv.w);
      ((float4*)(out + (size_t)d * 32))[lane] = v;
    }
  }
}

extern "C" void kernel_launch(void* const* d_in, const int* in_sizes, int n_in,
                              void* d_out, int out_size, void* d_ws, size_t ws_size,
                              hipStream_t stream) {
  const float* x   = (const float*)d_in[0];
  const int*   ei  = (const int*)d_in[1];
  const float* ea  = (const float*)d_in[2];
  const int*   etp = (const int*)d_in[3];
  const float* w1  = (const float*)d_in[4];
  const float* q1  = (const float*)d_in[5];
  const float* k1  = (const float*)d_in[6];
  const float* e1  = (const float*)d_in[7];
  const float* le1 = (const float*)d_in[8];
  const float* b1  = (const float*)d_in[9];
  const float* w3  = (const float*)d_in[10];
  const float* q3  = (const float*)d_in[11];
  const float* k3  = (const float*)d_in[12];
  const float* e3  = (const float*)d_in[13];
  const float* le3 = (const float*)d_in[14];
  const float* b3  = (const float*)d_in[15];
  const int N = in_sizes[0] / 128;
  const int E = in_sizes[3];
  const int* srcp = ei;
  const int* dstp = ei + E;

  float* ws   = (float*)d_ws;
  float* xw   = ws;                                  // 4*N*128
  float* qn   = xw + (size_t)4 * N * 128;            // 4*N*4
  float* kn   = qn + (size_t)4 * N * 4;              // 4*N*4
  float* ekb  = kn + (size_t)4 * N * 4;              // E*4
  float* alph = ekb + (size_t)E * 4;                 // E*4
  float* hbuf = alph + (size_t)E * 4;                // N*128
  float* leeb = hbuf + (size_t)N * 128;              // 128
  int* deg      = (int*)(leeb + 128);                // N
  int* rowst    = deg + N;                           // N+1
  int* cursor   = rowst + N + 1;                     // N
  int* bsum     = cursor + N;                        // 256
  int* boff     = bsum + 256;                        // 256
  uintptr_t pe = (uintptr_t)(boff + 256);
  pe = (pe + 15) & ~(uintptr_t)15;
  int4* es      = (int4*)pe;                         // E int4
  uintptr_t pa = (uintptr_t)(es + E);
  pa = (pa + 255) & ~(uintptr_t)255;
  unsigned short* xhi  = (unsigned short*)pa;        // N*128
  unsigned short* xlo  = xhi + (size_t)N * 128;      // N*128
  unsigned short* whiT = xlo + (size_t)N * 128;      // 4*128*128
  unsigned short* wloT = whiT + 4 * 128 * 128;       // 4*128*128
  (void)ws_size; (void)n_in; (void)out_size;

  int qkb  = (4 * N + 63) / 64;
  int eb   = (E + 255) / 256;
  int nb4  = (N + 3) / 4;
  int nbs  = (N + 1023) / 1024;
  int pgy  = (N + 127) / 128;
  int cxb  = (N * 128 / 8 + 255) / 256;

  hipMemsetAsync(deg, 0, (size_t)N * sizeof(int), stream);
  hist_kernel<<<eb, 256, 0, stream>>>(dstp, deg, E);
  scanA_kernel<<<nbs, 256, 0, stream>>>(deg, bsum, N);
  scanB_kernel<<<1, 256, 0, stream>>>(bsum, boff, rowst, nbs, N);
  scanC_kernel<<<nbs, 256, 0, stream>>>(deg, boff, rowst, cursor, N);
  scatter_kernel<<<eb, 256, 0, stream>>>(srcp, dstp, etp, cursor, es, E);
  lee_kernel<<<1, 128, 0, stream>>>(le1, e1, le3, e3, leeb);

  for (int layer = 0; layer < 2; ++layer) {
    const float* xin = layer ? hbuf : x;
    const float* w   = layer ? w3 : w1;
    const float* q   = layer ? q3 : q1;
    const float* k   = layer ? k3 : k1;
    const float* leep = leeb + (layer ? 64 : 0);
    const float* bias = layer ? b3 : b1;
    float* outp = layer ? (float*)d_out : hbuf;

    convx_kernel<<<cxb, 256, 0, stream>>>(xin, xhi, xlo, N * 128 / 8);
    convw_kernel<<<dim3(128, 4), 128, 0, stream>>>(w, whiT, wloT);
    proj_mfma_kernel<<<dim3(4, pgy), 256, 0, stream>>>(xhi, xlo, whiT, wloT, xw, N);
    qk_kernel<<<qkb, 256, 0, stream>>>(xw, q, k, qn, kn, 4 * N);
    ek_kernel<<<eb, 256, 0, stream>>>(ea, leep, ekb, E);
    alpha_kernel<<<eb, 256, 0, stream>>>(es, qn, kn, ekb, alph, E, N);
    agg_kernel<<<nb4, 256, 0, stream>>>(es, rowst, alph, xw,
                                        bias, outp, N, layer == 0 ? 1 : 0);
  }
}

// Round 9
// 562.551 us; speedup vs baseline: 1.3312x; 1.0337x over previous
//
#include <hip/hip_runtime.h>

// RGATNetwork: 2x RGATConv (R=4, H=4, C=32, HC=128, F_E=16) on N=50k nodes, E=800k edges.
// R9: (1) qn/kn computed from x via folded weights wqk[r]=w[r]@{q,k} (skinny fp32
// GEMM; removes qk_kernel's 102 MB xw re-read). (2) alpha_kernel fused into agg
// pass 1 with online softmax (2 edge-sweeps instead of 3). (3) layer-2 convx
// fused into agg layer-1 epilogue (bf16 split written alongside hbuf).
// (4) agg gather unrolled to 8 edges/iter. Rest unchanged from R8.

#define NEG_SLOPE 0.2f
#define SOFT_EPS 1e-16f

typedef __attribute__((ext_vector_type(8))) short bf16x8;
typedef __attribute__((ext_vector_type(4))) float f32x4;
typedef __attribute__((ext_vector_type(4))) unsigned short u16x4;

__device__ __forceinline__ void bf16split(float f, unsigned short& h, unsigned short& l) {
  unsigned u = __float_as_uint(f);
  unsigned r = u + 0x7FFFu + ((u >> 16) & 1u);
  h = (unsigned short)(r >> 16);
  float fh = __uint_as_float(((unsigned)h) << 16);
  float d = f - fh;
  unsigned u2 = __float_as_uint(d);
  unsigned r2 = u2 + 0x7FFFu + ((u2 >> 16) & 1u);
  l = (unsigned short)(r2 >> 16);
}

// lee[f,h] = sum_o le[f,o]*e[o,h]  for both layers (t<64: layer1, t>=64: layer3)
__global__ void lee_kernel(const float* __restrict__ le1, const float* __restrict__ e1,
                           const float* __restrict__ le3, const float* __restrict__ e3,
                           float* __restrict__ lee) {
  int t = threadIdx.x;
  const float* le = (t < 64) ? le1 : le3;
  const float* ee = (t < 64) ? e1 : e3;
  int u = t & 63, f = u >> 2, h = u & 3;
  float acc = 0.f;
  for (int o = 0; o < 128; ++o) acc += le[f * 128 + o] * ee[o * 4 + h];
  lee[t] = acc;
}

// wqk[L][r][f][j] = sum_o w[r,f,o] * {q(j<4) | k(j>=4)}[o, j&3]   (8192 outputs)
__global__ __launch_bounds__(256) void wqk_kernel(
    const float* __restrict__ w1, const float* __restrict__ q1, const float* __restrict__ k1,
    const float* __restrict__ w3, const float* __restrict__ q3, const float* __restrict__ k3,
    float* __restrict__ wqk) {
  int idx = blockIdx.x * 256 + threadIdx.x;
  int L = idx >> 12, rem = idx & 4095;
  int r = rem >> 10, rem2 = rem & 1023, f = rem2 >> 3, j = rem2 & 7;
  const float* w = L ? w3 : w1;
  const float* qk = (j < 4) ? (L ? q3 : q1) : (L ? k3 : k1);
  int h = j & 3;
  const float* wrow = w + ((size_t)r * 128 + f) * 128;
  float acc = 0.f;
  for (int o = 0; o < 128; ++o) acc += wrow[o] * qk[o * 4 + h];
  wqk[idx] = acc;
}

// ---- CSR build ----
__global__ __launch_bounds__(256) void hist_kernel(const int* __restrict__ dst,
                                                   int* __restrict__ deg, int E) {
  int e = blockIdx.x * 256 + threadIdx.x;
  if (e < E) atomicAdd(&deg[dst[e]], 1);
}

__global__ __launch_bounds__(256) void scanA_kernel(const int* __restrict__ deg,
                                                    int* __restrict__ bsum, int N) {
  int b = blockIdx.x, t = threadIdx.x;
  int base = b * 1024 + t * 4;
  int s = 0;
#pragma unroll
  for (int j = 0; j < 4; ++j) {
    int i = base + j;
    if (i < N) s += deg[i];
  }
#pragma unroll
  for (int o = 1; o < 64; o <<= 1) s += __shfl_xor(s, o);
  __shared__ int wsum[4];
  if ((t & 63) == 0) wsum[t >> 6] = s;
  __syncthreads();
  if (t == 0) bsum[b] = wsum[0] + wsum[1] + wsum[2] + wsum[3];
}

__global__ __launch_bounds__(256) void scanB_kernel(const int* __restrict__ bsum,
                                                    int* __restrict__ boff,
                                                    int* __restrict__ row_start,
                                                    int nb, int N) {
  int t = threadIdx.x;
  int v = (t < nb) ? bsum[t] : 0;
  int inc = v;
#pragma unroll
  for (int o = 1; o < 64; o <<= 1) {
    int u = __shfl_up(inc, o);
    if ((t & 63) >= o) inc += u;
  }
  __shared__ int wt[4];
  if ((t & 63) == 63) wt[t >> 6] = inc;
  __syncthreads();
  int add = 0;
  for (int wv = 0; wv < (t >> 6); ++wv) add += wt[wv];
  inc += add;
  if (t < nb) boff[t] = inc - v;
  if (t == 255) row_start[N] = inc;
}

__global__ __launch_bounds__(256) void scanC_kernel(const int* __restrict__ deg,
                                                    const int* __restrict__ boff,
                                                    int* __restrict__ row_start,
                                                    int* __restrict__ cursor, int N) {
  int b = blockIdx.x, t = threadIdx.x;
  int base = b * 1024 + t * 4;
  int d[4];
  int s = 0;
#pragma unroll
  for (int j = 0; j < 4; ++j) {
    int i = base + j;
    d[j] = (i < N) ? deg[i] : 0;
    s += d[j];
  }
  int inc = s;
#pragma unroll
  for (int o = 1; o < 64; o <<= 1) {
    int u = __shfl_up(inc, o);
    if ((t & 63) >= o) inc += u;
  }
  __shared__ int wt[4];
  if ((t & 63) == 63) wt[t >> 6] = inc;
  __syncthreads();
  int add = boff[b];
  for (int wv = 0; wv < (t >> 6); ++wv) add += wt[wv];
  int off = add + inc - s;
#pragma unroll
  for (int j = 0; j < 4; ++j) {
    int i = base + j;
    if (i < N) {
      row_start[i] = off;
      cursor[i] = off;
      off += d[j];
    }
  }
}

// packed scatter: es[pos] = {src, dst, et, eid}
__global__ __launch_bounds__(256) void scatter_kernel(
    const int* __restrict__ src, const int* __restrict__ dst, const int* __restrict__ et,
    int* __restrict__ cursor, int4* __restrict__ es, int E) {
  int e = blockIdx.x * 256 + threadIdx.x;
  if (e >= E) return;
  int d = dst[e];
  int pos = atomicAdd(&cursor[d], 1);
  es[pos] = make_int4(src[e], d, et[e], e);
}

// ---- bf16 split conversion (layer-1 input only; layer-2 fused into agg) ----
__global__ __launch_bounds__(256) void convx_kernel(const float* __restrict__ in,
                                                    unsigned short* __restrict__ hi,
                                                    unsigned short* __restrict__ lo,
                                                    int total8) {
  int i = blockIdx.x * 256 + threadIdx.x;
  if (i >= total8) return;
  const float4* p = (const float4*)in + (size_t)i * 2;
  float4 a = p[0], b = p[1];
  float v[8] = {a.x, a.y, a.z, a.w, b.x, b.y, b.z, b.w};
  bf16x8 hv, lv;
#pragma unroll
  for (int j = 0; j < 8; ++j) {
    unsigned short h, l;
    bf16split(v[j], h, l);
    hv[j] = (short)h; lv[j] = (short)l;
  }
  *(bf16x8*)(hi + (size_t)i * 8) = hv;
  *(bf16x8*)(lo + (size_t)i * 8) = lv;
}

__global__ void convw_kernel(const float* __restrict__ w,
                             unsigned short* __restrict__ hiT,
                             unsigned short* __restrict__ loT) {
  int f = blockIdx.x, r = blockIdx.y, o = threadIdx.x;
  float v = w[((size_t)r * 128 + f) * 128 + o];
  unsigned short h, l;
  bf16split(v, h, l);
  hiT[((size_t)r * 128 + o) * 128 + f] = h;
  loT[((size_t)r * 128 + o) * 128 + f] = l;
}

// ---- proj via MFMA, w staged in LDS fragment-major (unchanged from R7) ----
__global__ __launch_bounds__(256) void proj_mfma_kernel(
    const unsigned short* __restrict__ xhi, const unsigned short* __restrict__ xlo,
    const unsigned short* __restrict__ whiT, const unsigned short* __restrict__ wloT,
    float* __restrict__ xw, int N) {
  __shared__ bf16x8 wl_h[2048];  // 32 KB
  __shared__ bf16x8 wl_l[2048];  // 32 KB
  int r = blockIdx.x;
  int nb = blockIdx.y * 128;
  int t = threadIdx.x;
  const unsigned short* wh = whiT + (size_t)r * (128 * 128);
  const unsigned short* wl = wloT + (size_t)r * (128 * 128);

#pragma unroll
  for (int j = 0; j < 8; ++j) {
    int i = j * 256 + t;
    int c = i & 15, q = (i >> 4) & 3, kc = (i >> 6) & 3, ot = i >> 8;
    int srco = (ot * 16 + c) * 128 + kc * 32 + q * 8;
    wl_h[i] = *(const bf16x8*)(wh + srco);
    wl_l[i] = *(const bf16x8*)(wl + srco);
  }
  __syncthreads();

  int wv = t >> 6;
  int lane = t & 63;
  int c = lane & 15, q = lane >> 4;
  int nodebase = nb + wv * 32;
  int n0 = nodebase + c;
  int n1 = nodebase + 16 + c;
  int n0c = n0 < N ? n0 : N - 1;
  int n1c = n1 < N ? n1 : N - 1;

  f32x4 acc[8][2];
#pragma unroll
  for (int ot = 0; ot < 8; ++ot)
#pragma unroll
    for (int nt = 0; nt < 2; ++nt) acc[ot][nt] = (f32x4){0.f, 0.f, 0.f, 0.f};

  bf16x8 xb[2][4];
  {
    int k0 = q * 8;
    xb[0][0] = *(const bf16x8*)(xhi + (size_t)n0c * 128 + k0);
    xb[0][1] = *(const bf16x8*)(xlo + (size_t)n0c * 128 + k0);
    xb[0][2] = *(const bf16x8*)(xhi + (size_t)n1c * 128 + k0);
    xb[0][3] = *(const bf16x8*)(xlo + (size_t)n1c * 128 + k0);
  }
#pragma unroll
  for (int kc = 0; kc < 4; ++kc) {
    if (kc < 3) {
      int k0 = (kc + 1) * 32 + q * 8;
      xb[(kc + 1) & 1][0] = *(const bf16x8*)(xhi + (size_t)n0c * 128 + k0);
      xb[(kc + 1) & 1][1] = *(const bf16x8*)(xlo + (size_t)n0c * 128 + k0);
      xb[(kc + 1) & 1][2] = *(const bf16x8*)(xhi + (size_t)n1c * 128 + k0);
      xb[(kc + 1) & 1][3] = *(const bf16x8*)(xlo + (size_t)n1c * 128 + k0);
    }
    bf16x8 b0h = xb[kc & 1][0], b0l = xb[kc & 1][1];
    bf16x8 b1h = xb[kc & 1][2], b1l = xb[kc & 1][3];
#pragma unroll
    for (int ot = 0; ot < 8; ++ot) {
      int fi = ((ot * 4 + kc) * 4 + q) * 16 + c;
      bf16x8 ah = wl_h[fi];
      bf16x8 al = wl_l[fi];
      acc[ot][0] = __builtin_amdgcn_mfma_f32_16x16x32_bf16(ah, b0h, acc[ot][0], 0, 0, 0);
      acc[ot][0] = __builtin_amdgcn_mfma_f32_16x16x32_bf16(ah, b0l, acc[ot][0], 0, 0, 0);
      acc[ot][0] = __builtin_amdgcn_mfma_f32_16x16x32_bf16(al, b0h, acc[ot][0], 0, 0, 0);
      acc[ot][1] = __builtin_amdgcn_mfma_f32_16x16x32_bf16(ah, b1h, acc[ot][1], 0, 0, 0);
      acc[ot][1] = __builtin_amdgcn_mfma_f32_16x16x32_bf16(ah, b1l, acc[ot][1], 0, 0, 0);
      acc[ot][1] = __builtin_amdgcn_mfma_f32_16x16x32_bf16(al, b1h, acc[ot][1], 0, 0, 0);
    }
  }

#pragma unroll
  for (int nt = 0; nt < 2; ++nt) {
    int n = nodebase + nt * 16 + c;
    if (n < N) {
      float* base = xw + ((size_t)r * N + n) * 128 + q * 4;
#pragma unroll
      for (int ot = 0; ot < 8; ++ot)
        *(f32x4*)(base + ot * 16) = acc[ot][nt];
    }
  }
}

// qn/kn from x directly via folded wqk: qn[r,n,h] = x[n,:] @ wqk[r][:,h]
// block 256 = 64 nodes x 4 relations; wqk LDS stride 1032 spreads r across banks.
__global__ __launch_bounds__(256) void qkx_kernel(
    const float* __restrict__ xin, const float* __restrict__ wqk,
    float* __restrict__ qn, float* __restrict__ kn, int N) {
  __shared__ float sx[64 * 132];
  __shared__ float swqk[4 * 1032];
  int nb = blockIdx.x * 64;
  int t = threadIdx.x;
#pragma unroll
  for (int j = 0; j < 16; ++j) {
    int i = j * 256 + t;
    swqk[(i >> 10) * 1032 + (i & 1023)] = wqk[i];
  }
#pragma unroll
  for (int j = 0; j < 8; ++j) {
    int i = j * 256 + t;
    int n = nb + (i >> 5); if (n >= N) n = N - 1;
    ((float4*)sx)[(i >> 5) * 33 + (i & 31)] =
        ((const float4*)(xin + (size_t)n * 128))[i & 31];
  }
  __syncthreads();
  int rl = t >> 2, r = t & 3;
  float aq0 = 0, aq1 = 0, aq2 = 0, aq3 = 0;
  float ak0 = 0, ak1 = 0, ak2 = 0, ak3 = 0;
  const float* xr = sx + rl * 132;
  const float* wb = swqk + r * 1032;
  for (int f = 0; f < 128; ++f) {
    float xv = xr[f];
    float4 qw = *(const float4*)(wb + f * 8);
    float4 kw = *(const float4*)(wb + f * 8 + 4);
    aq0 += xv * qw.x; aq1 += xv * qw.y; aq2 += xv * qw.z; aq3 += xv * qw.w;
    ak0 += xv * kw.x; ak1 += xv * kw.y; ak2 += xv * kw.z; ak3 += xv * kw.w;
  }
  int n = nb + rl;
  if (n < N) {
    *(float4*)(qn + ((size_t)r * N + n) * 4) = make_float4(aq0, aq1, aq2, aq3);
    *(float4*)(kn + ((size_t)r * N + n) * 4) = make_float4(ak0, ak1, ak2, ak3);
  }
}

// ek[e,h] = sum_{f<16} ea[e,f]*lee[f,h]
__global__ __launch_bounds__(256) void ek_kernel(const float* __restrict__ ea,
                                                 const float* __restrict__ lee,
                                                 float* __restrict__ ek, int E) {
  __shared__ float sl[64];
  if (threadIdx.x < 64) sl[threadIdx.x] = lee[threadIdx.x];
  __syncthreads();
  int e = blockIdx.x * 256 + threadIdx.x;
  if (e >= E) return;
  const float4* a4 = (const float4*)(ea + (size_t)e * 16);
  float acc[4] = {0, 0, 0, 0};
#pragma unroll
  for (int i = 0; i < 4; ++i) {
    float4 v = a4[i];
    int f = i * 4;
#pragma unroll
    for (int h = 0; h < 4; ++h) {
      acc[h] += v.x * sl[f * 4 + h] + v.y * sl[(f + 1) * 4 + h] +
                v.z * sl[(f + 2) * 4 + h] + v.w * sl[(f + 3) * 4 + h];
    }
  }
  *(float4*)(ek + (size_t)e * 4) = make_float4(acc[0], acc[1], acc[2], acc[3]);
}

// fused alpha + online softmax + gather-aggregate + epilogue. One wave per dst node.
__global__ __launch_bounds__(256) void agg_kernel(
    const int4* __restrict__ es, const int* __restrict__ row_start,
    const float* __restrict__ qn, const float* __restrict__ kn,
    const float* __restrict__ ekb, float* __restrict__ alpha_s,
    const float* __restrict__ xw, const float* __restrict__ bias,
    float* __restrict__ out, unsigned short* __restrict__ xhi,
    unsigned short* __restrict__ xlo, int N, int concat) {
  int d = blockIdx.x * 4 + (threadIdx.x >> 6);
  if (d >= N) return;
  int lane = threadIdx.x & 63;
  int rs = row_start[d], re = row_start[d + 1];

  float4 qv0 = *(const float4*)(qn + (size_t)d * 4);
  float4 qv1 = *(const float4*)(qn + ((size_t)N + d) * 4);
  float4 qv2 = *(const float4*)(qn + ((size_t)2 * N + d) * 4);
  float4 qv3 = *(const float4*)(qn + ((size_t)3 * N + d) * 4);

  // pass 1: alpha = lrelu(q+k+ek) -> alpha_s; online (m,s) per head
  float4 m = make_float4(-1e30f, -1e30f, -1e30f, -1e30f);
  float4 s = make_float4(0.f, 0.f, 0.f, 0.f);
  for (int i = rs + lane; i < re; i += 64) {
    int4 v = es[i];
    float4 kv = *(const float4*)(kn + ((size_t)v.z * N + v.x) * 4);
    float4 ev = *(const float4*)(ekb + (size_t)v.w * 4);
    float4 q4 = (v.z == 0) ? qv0 : (v.z == 1) ? qv1 : (v.z == 2) ? qv2 : qv3;
    float4 a = make_float4(q4.x + kv.x + ev.x, q4.y + kv.y + ev.y,
                           q4.z + kv.z + ev.z, q4.w + kv.w + ev.w);
    a.x = a.x > 0.f ? a.x : NEG_SLOPE * a.x;
    a.y = a.y > 0.f ? a.y : NEG_SLOPE * a.y;
    a.z = a.z > 0.f ? a.z : NEG_SLOPE * a.z;
    a.w = a.w > 0.f ? a.w : NEG_SLOPE * a.w;
    ((float4*)alpha_s)[i] = a;
    float4 M = make_float4(fmaxf(m.x, a.x), fmaxf(m.y, a.y),
                           fmaxf(m.z, a.z), fmaxf(m.w, a.w));
    s.x = s.x * __expf(m.x - M.x) + __expf(a.x - M.x);
    s.y = s.y * __expf(m.y - M.y) + __expf(a.y - M.y);
    s.z = s.z * __expf(m.z - M.z) + __expf(a.z - M.z);
    s.w = s.w * __expf(m.w - M.w) + __expf(a.w - M.w);
    m = M;
  }
#pragma unroll
  for (int o = 32; o >= 1; o >>= 1) {
    float4 mo = make_float4(__shfl_xor(m.x, o), __shfl_xor(m.y, o),
                            __shfl_xor(m.z, o), __shfl_xor(m.w, o));
    float4 so = make_float4(__shfl_xor(s.x, o), __shfl_xor(s.y, o),
                            __shfl_xor(s.z, o), __shfl_xor(s.w, o));
    float4 M = make_float4(fmaxf(m.x, mo.x), fmaxf(m.y, mo.y),
                           fmaxf(m.z, mo.z), fmaxf(m.w, mo.w));
    s.x = s.x * __expf(m.x - M.x) + so.x * __expf(mo.x - M.x);
    s.y = s.y * __expf(m.y - M.y) + so.y * __expf(mo.y - M.y);
    s.z = s.z * __expf(m.z - M.z) + so.z * __expf(mo.z - M.z);
    s.w = s.w * __expf(m.w - M.w) + so.w * __expf(mo.w - M.w);
    m = M;
  }

  int half = lane >> 5;
  int cl = lane & 31;
  int h = cl >> 3;
  float mxh = (h == 0) ? m.x : (h == 1) ? m.y : (h == 2) ? m.z : m.w;
  float smh = (h == 0) ? s.x : (h == 1) ? s.y : (h == 2) ? s.z : s.w;
  float rden = 1.f / (smh + SOFT_EPS);

  // pass 2: gather, 32 lanes/edge x float4, 8 edges per unrolled iteration
  float4 acc = make_float4(0.f, 0.f, 0.f, 0.f);
  int base = rs;
  for (; base + 8 <= re; base += 8) {
    int e0 = base + half, e1 = base + 2 + half, e2 = base + 4 + half, e3 = base + 6 + half;
    int4 a0 = es[e0], a1 = es[e1], a2 = es[e2], a3 = es[e3];
    float w0 = __expf(alpha_s[(size_t)e0 * 4 + h] - mxh);
    float w1 = __expf(alpha_s[(size_t)e1 * 4 + h] - mxh);
    float w2 = __expf(alpha_s[(size_t)e2 * 4 + h] - mxh);
    float w3 = __expf(alpha_s[(size_t)e3 * 4 + h] - mxh);
    float4 x0 = *(const float4*)(xw + ((size_t)a0.z * N + a0.x) * 128 + cl * 4);
    float4 x1 = *(const float4*)(xw + ((size_t)a1.z * N + a1.x) * 128 + cl * 4);
    float4 x2 = *(const float4*)(xw + ((size_t)a2.z * N + a2.x) * 128 + cl * 4);
    float4 x3 = *(const float4*)(xw + ((size_t)a3.z * N + a3.x) * 128 + cl * 4);
    acc.x += w0 * x0.x + w1 * x1.x + w2 * x2.x + w3 * x3.x;
    acc.y += w0 * x0.y + w1 * x1.y + w2 * x2.y + w3 * x3.y;
    acc.z += w0 * x0.z + w1 * x1.z + w2 * x2.z + w3 * x3.z;
    acc.w += w0 * x0.w + w1 * x1.w + w2 * x2.w + w3 * x3.w;
  }
  for (; base < re; base += 2) {
    int e = base + half;
    if (e < re) {
      int4 a = es[e];
      float w = __expf(alpha_s[(size_t)e * 4 + h] - mxh);
      float4 xv = *(const float4*)(xw + ((size_t)a.z * N + a.x) * 128 + cl * 4);
      acc.x += w * xv.x; acc.y += w * xv.y; acc.z += w * xv.z; acc.w += w * xv.w;
    }
  }
  acc.x *= rden; acc.y *= rden; acc.z *= rden; acc.w *= rden;
  acc.x += __shfl_xor(acc.x, 32); acc.y += __shfl_xor(acc.y, 32);
  acc.z += __shfl_xor(acc.z, 32); acc.w += __shfl_xor(acc.w, 32);

  if (concat) {  // layer 1: relu(agg+b1) -> hbuf, plus fused bf16 split for layer-2 proj
    if (half == 0) {
      float4 bv = ((const float4*)bias)[cl];
      float4 v = make_float4(acc.x + bv.x, acc.y + bv.y, acc.z + bv.z, acc.w + bv.w);
      v.x = v.x > 0.f ? v.x : 0.f;
      v.y = v.y > 0.f ? v.y : 0.f;
      v.z = v.z > 0.f ? v.z : 0.f;
      v.w = v.w > 0.f ? v.w : 0.f;
      ((float4*)(out + (size_t)d * 128))[cl] = v;
      u16x4 hv, lv;
      unsigned short hh, ll;
      bf16split(v.x, hh, ll); hv[0] = hh; lv[0] = ll;
      bf16split(v.y, hh, ll); hv[1] = hh; lv[1] = ll;
      bf16split(v.z, hh, ll); hv[2] = hh; lv[2] = ll;
      bf16split(v.w, hh, ll); hv[3] = hh; lv[3] = ll;
      *(u16x4*)(xhi + (size_t)d * 128 + cl * 4) = hv;
      *(u16x4*)(xlo + (size_t)d * 128 + cl * 4) = lv;
    }
  } else {       // layer 2: mean over 4 heads + b3 -> out[d,32]
    acc.x += __shfl_xor(acc.x, 8);  acc.y += __shfl_xor(acc.y, 8);
    acc.z += __shfl_xor(acc.z, 8);  acc.w += __shfl_xor(acc.w, 8);
    acc.x += __shfl_xor(acc.x, 16); acc.y += __shfl_xor(acc.y, 16);
    acc.z += __shfl_xor(acc.z, 16); acc.w += __shfl_xor(acc.w, 16);
    if (lane < 8) {
      float4 bv = ((const float4*)bias)[lane];
      float4 v = make_float4(0.25f * acc.x + bv.x, 0.25f * acc.y + bv.y,
                             0.25f * acc.z + bv.z, 0.25f * acc.w + bv.w);
      ((float4*)(out + (size_t)d * 32))[lane] = v;
    }
  }
}

extern "C" void kernel_launch(void* const* d_in, const int* in_sizes, int n_in,
                              void* d_out, int out_size, void* d_ws, size_t ws_size,
                              hipStream_t stream) {
  const float* x   = (const float*)d_in[0];
  const int*   ei  = (const int*)d_in[1];
  const float* ea  = (const float*)d_in[2];
  const int*   etp = (const int*)d_in[3];
  const float* w1  = (const float*)d_in[4];
  const float* q1  = (const float*)d_in[5];
  const float* k1  = (const float*)d_in[6];
  const float* e1  = (const float*)d_in[7];
  const float* le1 = (const float*)d_in[8];
  const float* b1  = (const float*)d_in[9];
  const float* w3  = (const float*)d_in[10];
  const float* q3  = (const float*)d_in[11];
  const float* k3  = (const float*)d_in[12];
  const float* e3  = (const float*)d_in[13];
  const float* le3 = (const float*)d_in[14];
  const float* b3  = (const float*)d_in[15];
  const int N = in_sizes[0] / 128;
  const int E = in_sizes[3];
  const int* srcp = ei;
  const int* dstp = ei + E;

  float* ws   = (float*)d_ws;
  float* xw   = ws;                                  // 4*N*128
  float* qn   = xw + (size_t)4 * N * 128;            // 4*N*4
  float* kn   = qn + (size_t)4 * N * 4;              // 4*N*4
  float* ekb  = kn + (size_t)4 * N * 4;              // E*4
  float* alph = ekb + (size_t)E * 4;                 // E*4
  float* hbuf = alph + (size_t)E * 4;                // N*128
  float* leeb = hbuf + (size_t)N * 128;              // 128
  float* wqkb = leeb + 128;                          // 2*4*128*8 = 8192
  int* deg      = (int*)(wqkb + 8192);               // N
  int* rowst    = deg + N;                           // N+1
  int* cursor   = rowst + N + 1;                     // N
  int* bsum     = cursor + N;                        // 256
  int* boff     = bsum + 256;                        // 256
  uintptr_t pe = (uintptr_t)(boff + 256);
  pe = (pe + 15) & ~(uintptr_t)15;
  int4* es      = (int4*)pe;                         // E int4
  uintptr_t pa = (uintptr_t)(es + E);
  pa = (pa + 255) & ~(uintptr_t)255;
  unsigned short* xhi  = (unsigned short*)pa;        // N*128
  unsigned short* xlo  = xhi + (size_t)N * 128;      // N*128
  unsigned short* whiT = xlo + (size_t)N * 128;      // 4*128*128
  unsigned short* wloT = whiT + 4 * 128 * 128;       // 4*128*128
  (void)ws_size; (void)n_in; (void)out_size;

  int eb   = (E + 255) / 256;
  int nb4  = (N + 3) / 4;
  int nbs  = (N + 1023) / 1024;
  int pgy  = (N + 127) / 128;
  int qxb  = (N + 63) / 64;
  int cxb  = (N * 128 / 8 + 255) / 256;

  hipMemsetAsync(deg, 0, (size_t)N * sizeof(int), stream);
  hist_kernel<<<eb, 256, 0, stream>>>(dstp, deg, E);
  scanA_kernel<<<nbs, 256, 0, stream>>>(deg, bsum, N);
  scanB_kernel<<<1, 256, 0, stream>>>(bsum, boff, rowst, nbs, N);
  scanC_kernel<<<nbs, 256, 0, stream>>>(deg, boff, rowst, cursor, N);
  scatter_kernel<<<eb, 256, 0, stream>>>(srcp, dstp, etp, cursor, es, E);
  lee_kernel<<<1, 128, 0, stream>>>(le1, e1, le3, e3, leeb);
  wqk_kernel<<<32, 256, 0, stream>>>(w1, q1, k1, w3, q3, k3, wqkb);
  convx_kernel<<<cxb, 256, 0, stream>>>(x, xhi, xlo, N * 128 / 8);

  for (int layer = 0; layer < 2; ++layer) {
    const float* xin = layer ? hbuf : x;
    const float* w   = layer ? w3 : w1;
    const float* leep = leeb + (layer ? 64 : 0);
    const float* bias = layer ? b3 : b1;
    float* outp = layer ? (float*)d_out : hbuf;

    convw_kernel<<<dim3(128, 4), 128, 0, stream>>>(w, whiT, wloT);
    proj_mfma_kernel<<<dim3(4, pgy), 256, 0, stream>>>(xhi, xlo, whiT, wloT, xw, N);
    qkx_kernel<<<qxb, 256, 0, stream>>>(xin, wqkb + layer * 4096, qn, kn, N);
    ek_kernel<<<eb, 256, 0, stream>>>(ea, leep, ekb, E);
    agg_kernel<<<nb4, 256, 0, stream>>>(es, rowst, qn, kn, ekb, alph, xw,
                                        bias, outp, xhi, xlo, N, layer == 0 ? 1 : 0);
  }
}

// Round 10
// 508.683 us; speedup vs baseline: 1.4721x; 1.1059x over previous
//
#include <hip/hip_runtime.h>

// RGATNetwork: 2x RGATConv (R=4, H=4, C=32, HC=128, F_E=16) on N=50k nodes, E=800k edges.
// R10: (1) xw stored as fp16 (proj epilogue converts; agg gathers half8 with
// 16 lanes/edge): halves proj writes (100->50 MB/layer) and agg's dominant
// gather (~190->~95 MB/layer). fp16 not bf16: 4x finer mantissa, range safe.
// (2) ek computed ONCE for both layers in dst-sorted position (ek2_kernel:
// ea rows gathered by eid = full 64B lines, eks written sequential) -> agg
// pass 1 reads eks as a stream (removes 51 MB/layer of 4x-amplified gathers).
// Rest unchanged from R9.

#define NEG_SLOPE 0.2f
#define SOFT_EPS 1e-16f

typedef __attribute__((ext_vector_type(8))) short bf16x8;
typedef __attribute__((ext_vector_type(4))) float f32x4;
typedef __attribute__((ext_vector_type(4))) unsigned short u16x4;
typedef __attribute__((ext_vector_type(4))) _Float16 half4;
typedef __attribute__((ext_vector_type(8))) _Float16 half8;

__device__ __forceinline__ void bf16split(float f, unsigned short& h, unsigned short& l) {
  unsigned u = __float_as_uint(f);
  unsigned r = u + 0x7FFFu + ((u >> 16) & 1u);
  h = (unsigned short)(r >> 16);
  float fh = __uint_as_float(((unsigned)h) << 16);
  float d = f - fh;
  unsigned u2 = __float_as_uint(d);
  unsigned r2 = u2 + 0x7FFFu + ((u2 >> 16) & 1u);
  l = (unsigned short)(r2 >> 16);
}

// lee[f,h]: t<64 layer1, t>=64 layer3
__global__ void lee_kernel(const float* __restrict__ le1, const float* __restrict__ e1,
                           const float* __restrict__ le3, const float* __restrict__ e3,
                           float* __restrict__ lee) {
  int t = threadIdx.x;
  const float* le = (t < 64) ? le1 : le3;
  const float* ee = (t < 64) ? e1 : e3;
  int u = t & 63, f = u >> 2, h = u & 3;
  float acc = 0.f;
  for (int o = 0; o < 128; ++o) acc += le[f * 128 + o] * ee[o * 4 + h];
  lee[t] = acc;
}

// wqk[L][r][f][j] = sum_o w[r,f,o] * {q|k}[o, j&3]
__global__ __launch_bounds__(256) void wqk_kernel(
    const float* __restrict__ w1, const float* __restrict__ q1, const float* __restrict__ k1,
    const float* __restrict__ w3, const float* __restrict__ q3, const float* __restrict__ k3,
    float* __restrict__ wqk) {
  int idx = blockIdx.x * 256 + threadIdx.x;
  int L = idx >> 12, rem = idx & 4095;
  int r = rem >> 10, rem2 = rem & 1023, f = rem2 >> 3, j = rem2 & 7;
  const float* w = L ? w3 : w1;
  const float* qk = (j < 4) ? (L ? q3 : q1) : (L ? k3 : k1);
  int h = j & 3;
  const float* wrow = w + ((size_t)r * 128 + f) * 128;
  float acc = 0.f;
  for (int o = 0; o < 128; ++o) acc += wrow[o] * qk[o * 4 + h];
  wqk[idx] = acc;
}

// ---- CSR build ----
__global__ __launch_bounds__(256) void hist_kernel(const int* __restrict__ dst,
                                                   int* __restrict__ deg, int E) {
  int e = blockIdx.x * 256 + threadIdx.x;
  if (e < E) atomicAdd(&deg[dst[e]], 1);
}

__global__ __launch_bounds__(256) void scanA_kernel(const int* __restrict__ deg,
                                                    int* __restrict__ bsum, int N) {
  int b = blockIdx.x, t = threadIdx.x;
  int base = b * 1024 + t * 4;
  int s = 0;
#pragma unroll
  for (int j = 0; j < 4; ++j) {
    int i = base + j;
    if (i < N) s += deg[i];
  }
#pragma unroll
  for (int o = 1; o < 64; o <<= 1) s += __shfl_xor(s, o);
  __shared__ int wsum[4];
  if ((t & 63) == 0) wsum[t >> 6] = s;
  __syncthreads();
  if (t == 0) bsum[b] = wsum[0] + wsum[1] + wsum[2] + wsum[3];
}

__global__ __launch_bounds__(256) void scanB_kernel(const int* __restrict__ bsum,
                                                    int* __restrict__ boff,
                                                    int* __restrict__ row_start,
                                                    int nb, int N) {
  int t = threadIdx.x;
  int v = (t < nb) ? bsum[t] : 0;
  int inc = v;
#pragma unroll
  for (int o = 1; o < 64; o <<= 1) {
    int u = __shfl_up(inc, o);
    if ((t & 63) >= o) inc += u;
  }
  __shared__ int wt[4];
  if ((t & 63) == 63) wt[t >> 6] = inc;
  __syncthreads();
  int add = 0;
  for (int wv = 0; wv < (t >> 6); ++wv) add += wt[wv];
  inc += add;
  if (t < nb) boff[t] = inc - v;
  if (t == 255) row_start[N] = inc;
}

__global__ __launch_bounds__(256) void scanC_kernel(const int* __restrict__ deg,
                                                    const int* __restrict__ boff,
                                                    int* __restrict__ row_start,
                                                    int* __restrict__ cursor, int N) {
  int b = blockIdx.x, t = threadIdx.x;
  int base = b * 1024 + t * 4;
  int d[4];
  int s = 0;
#pragma unroll
  for (int j = 0; j < 4; ++j) {
    int i = base + j;
    d[j] = (i < N) ? deg[i] : 0;
    s += d[j];
  }
  int inc = s;
#pragma unroll
  for (int o = 1; o < 64; o <<= 1) {
    int u = __shfl_up(inc, o);
    if ((t & 63) >= o) inc += u;
  }
  __shared__ int wt[4];
  if ((t & 63) == 63) wt[t >> 6] = inc;
  __syncthreads();
  int add = boff[b];
  for (int wv = 0; wv < (t >> 6); ++wv) add += wt[wv];
  int off = add + inc - s;
#pragma unroll
  for (int j = 0; j < 4; ++j) {
    int i = base + j;
    if (i < N) {
      row_start[i] = off;
      cursor[i] = off;
      off += d[j];
    }
  }
}

// packed scatter: es[pos] = {src, dst, et, eid}
__global__ __launch_bounds__(256) void scatter_kernel(
    const int* __restrict__ src, const int* __restrict__ dst, const int* __restrict__ et,
    int* __restrict__ cursor, int4* __restrict__ es, int E) {
  int e = blockIdx.x * 256 + threadIdx.x;
  if (e >= E) return;
  int d = dst[e];
  int pos = atomicAdd(&cursor[d], 1);
  es[pos] = make_int4(src[e], d, et[e], e);
}

// ek for BOTH layers at dst-sorted position i: gathers ea[eid] (64B rows, no
// line amplification), writes eks1[i], eks3[i] sequentially.
__global__ __launch_bounds__(256) void ek2_kernel(
    const int4* __restrict__ es, const float* __restrict__ ea,
    const float* __restrict__ lee, float* __restrict__ eks1,
    float* __restrict__ eks3, int E) {
  __shared__ float sl[128];
  if (threadIdx.x < 128) sl[threadIdx.x] = lee[threadIdx.x];
  __syncthreads();
  int i = blockIdx.x * 256 + threadIdx.x;
  if (i >= E) return;
  int eid = es[i].w;
  const float4* a4 = (const float4*)(ea + (size_t)eid * 16);
  float a1[4] = {0, 0, 0, 0}, a3[4] = {0, 0, 0, 0};
#pragma unroll
  for (int ii = 0; ii < 4; ++ii) {
    float4 v = a4[ii];
    int f = ii * 4;
#pragma unroll
    for (int h = 0; h < 4; ++h) {
      a1[h] += v.x * sl[f * 4 + h] + v.y * sl[(f + 1) * 4 + h] +
               v.z * sl[(f + 2) * 4 + h] + v.w * sl[(f + 3) * 4 + h];
      a3[h] += v.x * sl[64 + f * 4 + h] + v.y * sl[64 + (f + 1) * 4 + h] +
               v.z * sl[64 + (f + 2) * 4 + h] + v.w * sl[64 + (f + 3) * 4 + h];
    }
  }
  *(float4*)(eks1 + (size_t)i * 4) = make_float4(a1[0], a1[1], a1[2], a1[3]);
  *(float4*)(eks3 + (size_t)i * 4) = make_float4(a3[0], a3[1], a3[2], a3[3]);
}

// ---- bf16 split conversion (layer-1 x only; layer-2 fused into agg) ----
__global__ __launch_bounds__(256) void convx_kernel(const float* __restrict__ in,
                                                    unsigned short* __restrict__ hi,
                                                    unsigned short* __restrict__ lo,
                                                    int total8) {
  int i = blockIdx.x * 256 + threadIdx.x;
  if (i >= total8) return;
  const float4* p = (const float4*)in + (size_t)i * 2;
  float4 a = p[0], b = p[1];
  float v[8] = {a.x, a.y, a.z, a.w, b.x, b.y, b.z, b.w};
  bf16x8 hv, lv;
#pragma unroll
  for (int j = 0; j < 8; ++j) {
    unsigned short h, l;
    bf16split(v[j], h, l);
    hv[j] = (short)h; lv[j] = (short)l;
  }
  *(bf16x8*)(hi + (size_t)i * 8) = hv;
  *(bf16x8*)(lo + (size_t)i * 8) = lv;
}

__global__ void convw_kernel(const float* __restrict__ w,
                             unsigned short* __restrict__ hiT,
                             unsigned short* __restrict__ loT) {
  int f = blockIdx.x, r = blockIdx.y, o = threadIdx.x;
  float v = w[((size_t)r * 128 + f) * 128 + o];
  unsigned short h, l;
  bf16split(v, h, l);
  hiT[((size_t)r * 128 + o) * 128 + f] = h;
  loT[((size_t)r * 128 + o) * 128 + f] = l;
}

// ---- proj via MFMA, w staged in LDS fragment-major; fp16 output ----
__global__ __launch_bounds__(256) void proj_mfma_kernel(
    const unsigned short* __restrict__ xhi, const unsigned short* __restrict__ xlo,
    const unsigned short* __restrict__ whiT, const unsigned short* __restrict__ wloT,
    _Float16* __restrict__ xwh, int N) {
  __shared__ bf16x8 wl_h[2048];  // 32 KB
  __shared__ bf16x8 wl_l[2048];  // 32 KB
  int r = blockIdx.x;
  int nb = blockIdx.y * 128;
  int t = threadIdx.x;
  const unsigned short* wh = whiT + (size_t)r * (128 * 128);
  const unsigned short* wl = wloT + (size_t)r * (128 * 128);

#pragma unroll
  for (int j = 0; j < 8; ++j) {
    int i = j * 256 + t;
    int c = i & 15, q = (i >> 4) & 3, kc = (i >> 6) & 3, ot = i >> 8;
    int srco = (ot * 16 + c) * 128 + kc * 32 + q * 8;
    wl_h[i] = *(const bf16x8*)(wh + srco);
    wl_l[i] = *(const bf16x8*)(wl + srco);
  }
  __syncthreads();

  int wv = t >> 6;
  int lane = t & 63;
  int c = lane & 15, q = lane >> 4;
  int nodebase = nb + wv * 32;
  int n0 = nodebase + c;
  int n1 = nodebase + 16 + c;
  int n0c = n0 < N ? n0 : N - 1;
  int n1c = n1 < N ? n1 : N - 1;

  f32x4 acc[8][2];
#pragma unroll
  for (int ot = 0; ot < 8; ++ot)
#pragma unroll
    for (int nt = 0; nt < 2; ++nt) acc[ot][nt] = (f32x4){0.f, 0.f, 0.f, 0.f};

  bf16x8 xb[2][4];
  {
    int k0 = q * 8;
    xb[0][0] = *(const bf16x8*)(xhi + (size_t)n0c * 128 + k0);
    xb[0][1] = *(const bf16x8*)(xlo + (size_t)n0c * 128 + k0);
    xb[0][2] = *(const bf16x8*)(xhi + (size_t)n1c * 128 + k0);
    xb[0][3] = *(const bf16x8*)(xlo + (size_t)n1c * 128 + k0);
  }
#pragma unroll
  for (int kc = 0; kc < 4; ++kc) {
    if (kc < 3) {
      int k0 = (kc + 1) * 32 + q * 8;
      xb[(kc + 1) & 1][0] = *(const bf16x8*)(xhi + (size_t)n0c * 128 + k0);
      xb[(kc + 1) & 1][1] = *(const bf16x8*)(xlo + (size_t)n0c * 128 + k0);
      xb[(kc + 1) & 1][2] = *(const bf16x8*)(xhi + (size_t)n1c * 128 + k0);
      xb[(kc + 1) & 1][3] = *(const bf16x8*)(xlo + (size_t)n1c * 128 + k0);
    }
    bf16x8 b0h = xb[kc & 1][0], b0l = xb[kc & 1][1];
    bf16x8 b1h = xb[kc & 1][2], b1l = xb[kc & 1][3];
#pragma unroll
    for (int ot = 0; ot < 8; ++ot) {
      int fi = ((ot * 4 + kc) * 4 + q) * 16 + c;
      bf16x8 ah = wl_h[fi];
      bf16x8 al = wl_l[fi];
      acc[ot][0] = __builtin_amdgcn_mfma_f32_16x16x32_bf16(ah, b0h, acc[ot][0], 0, 0, 0);
      acc[ot][0] = __builtin_amdgcn_mfma_f32_16x16x32_bf16(ah, b0l, acc[ot][0], 0, 0, 0);
      acc[ot][0] = __builtin_amdgcn_mfma_f32_16x16x32_bf16(al, b0h, acc[ot][0], 0, 0, 0);
      acc[ot][1] = __builtin_amdgcn_mfma_f32_16x16x32_bf16(ah, b1h, acc[ot][1], 0, 0, 0);
      acc[ot][1] = __builtin_amdgcn_mfma_f32_16x16x32_bf16(ah, b1l, acc[ot][1], 0, 0, 0);
      acc[ot][1] = __builtin_amdgcn_mfma_f32_16x16x32_bf16(al, b1h, acc[ot][1], 0, 0, 0);
    }
  }

#pragma unroll
  for (int nt = 0; nt < 2; ++nt) {
    int n = nodebase + nt * 16 + c;
    if (n < N) {
      _Float16* basep = xwh + ((size_t)r * N + n) * 128 + q * 4;
#pragma unroll
      for (int ot = 0; ot < 8; ++ot) {
        f32x4 a = acc[ot][nt];
        half4 hv;
        hv[0] = (_Float16)a.x; hv[1] = (_Float16)a.y;
        hv[2] = (_Float16)a.z; hv[3] = (_Float16)a.w;
        *(half4*)(basep + ot * 16) = hv;
      }
    }
  }
}

// qn/kn from x via folded wqk (unchanged from R9)
__global__ __launch_bounds__(256) void qkx_kernel(
    const float* __restrict__ xin, const float* __restrict__ wqk,
    float* __restrict__ qn, float* __restrict__ kn, int N) {
  __shared__ float sx[64 * 132];
  __shared__ float swqk[4 * 1032];
  int nb = blockIdx.x * 64;
  int t = threadIdx.x;
#pragma unroll
  for (int j = 0; j < 16; ++j) {
    int i = j * 256 + t;
    swqk[(i >> 10) * 1032 + (i & 1023)] = wqk[i];
  }
#pragma unroll
  for (int j = 0; j < 8; ++j) {
    int i = j * 256 + t;
    int n = nb + (i >> 5); if (n >= N) n = N - 1;
    ((float4*)sx)[(i >> 5) * 33 + (i & 31)] =
        ((const float4*)(xin + (size_t)n * 128))[i & 31];
  }
  __syncthreads();
  int rl = t >> 2, r = t & 3;
  float aq0 = 0, aq1 = 0, aq2 = 0, aq3 = 0;
  float ak0 = 0, ak1 = 0, ak2 = 0, ak3 = 0;
  const float* xr = sx + rl * 132;
  const float* wb = swqk + r * 1032;
  for (int f = 0; f < 128; ++f) {
    float xv = xr[f];
    float4 qw = *(const float4*)(wb + f * 8);
    float4 kw = *(const float4*)(wb + f * 8 + 4);
    aq0 += xv * qw.x; aq1 += xv * qw.y; aq2 += xv * qw.z; aq3 += xv * qw.w;
    ak0 += xv * kw.x; ak1 += xv * kw.y; ak2 += xv * kw.z; ak3 += xv * kw.w;
  }
  int n = nb + rl;
  if (n < N) {
    *(float4*)(qn + ((size_t)r * N + n) * 4) = make_float4(aq0, aq1, aq2, aq3);
    *(float4*)(kn + ((size_t)r * N + n) * 4) = make_float4(ak0, ak1, ak2, ak3);
  }
}

// fused alpha + online softmax + fp16 gather-aggregate + epilogue.
// One wave per dst node. Pass1: 1 lane/edge. Pass2: 16 lanes/edge (half8).
__global__ __launch_bounds__(256) void agg_kernel(
    const int4* __restrict__ es, const int* __restrict__ row_start,
    const float* __restrict__ qn, const float* __restrict__ kn,
    const float* __restrict__ eks, float* __restrict__ alpha_s,
    const _Float16* __restrict__ xwh, const float* __restrict__ bias,
    float* __restrict__ out, unsigned short* __restrict__ xhi,
    unsigned short* __restrict__ xlo, int N, int concat) {
  int d = blockIdx.x * 4 + (threadIdx.x >> 6);
  if (d >= N) return;
  int lane = threadIdx.x & 63;
  int rs = row_start[d], re = row_start[d + 1];

  float4 qv0 = *(const float4*)(qn + (size_t)d * 4);
  float4 qv1 = *(const float4*)(qn + ((size_t)N + d) * 4);
  float4 qv2 = *(const float4*)(qn + ((size_t)2 * N + d) * 4);
  float4 qv3 = *(const float4*)(qn + ((size_t)3 * N + d) * 4);

  // pass 1: alpha -> alpha_s; online (m,s) per head. eks read sequentially.
  float4 m = make_float4(-1e30f, -1e30f, -1e30f, -1e30f);
  float4 s = make_float4(0.f, 0.f, 0.f, 0.f);
  for (int i = rs + lane; i < re; i += 64) {
    int4 v = es[i];
    float4 kv = *(const float4*)(kn + ((size_t)v.z * N + v.x) * 4);
    float4 ev = *(const float4*)(eks + (size_t)i * 4);
    float4 q4 = (v.z == 0) ? qv0 : (v.z == 1) ? qv1 : (v.z == 2) ? qv2 : qv3;
    float4 a = make_float4(q4.x + kv.x + ev.x, q4.y + kv.y + ev.y,
                           q4.z + kv.z + ev.z, q4.w + kv.w + ev.w);
    a.x = a.x > 0.f ? a.x : NEG_SLOPE * a.x;
    a.y = a.y > 0.f ? a.y : NEG_SLOPE * a.y;
    a.z = a.z > 0.f ? a.z : NEG_SLOPE * a.z;
    a.w = a.w > 0.f ? a.w : NEG_SLOPE * a.w;
    ((float4*)alpha_s)[i] = a;
    float4 M = make_float4(fmaxf(m.x, a.x), fmaxf(m.y, a.y),
                           fmaxf(m.z, a.z), fmaxf(m.w, a.w));
    s.x = s.x * __expf(m.x - M.x) + __expf(a.x - M.x);
    s.y = s.y * __expf(m.y - M.y) + __expf(a.y - M.y);
    s.z = s.z * __expf(m.z - M.z) + __expf(a.z - M.z);
    s.w = s.w * __expf(m.w - M.w) + __expf(a.w - M.w);
    m = M;
  }
#pragma unroll
  for (int o = 32; o >= 1; o >>= 1) {
    float4 mo = make_float4(__shfl_xor(m.x, o), __shfl_xor(m.y, o),
                            __shfl_xor(m.z, o), __shfl_xor(m.w, o));
    float4 so = make_float4(__shfl_xor(s.x, o), __shfl_xor(s.y, o),
                            __shfl_xor(s.z, o), __shfl_xor(s.w, o));
    float4 M = make_float4(fmaxf(m.x, mo.x), fmaxf(m.y, mo.y),
                           fmaxf(m.z, mo.z), fmaxf(m.w, mo.w));
    s.x = s.x * __expf(m.x - M.x) + so.x * __expf(mo.x - M.x);
    s.y = s.y * __expf(m.y - M.y) + so.y * __expf(mo.y - M.y);
    s.z = s.z * __expf(m.z - M.z) + so.z * __expf(mo.z - M.z);
    s.w = s.w * __expf(m.w - M.w) + so.w * __expf(mo.w - M.w);
    m = M;
  }

  int quar = lane >> 4;  // which edge of the group of 4
  int cl = lane & 15;    // 8-channel group within the 128-wide row
  int h = cl >> 2;       // head
  float mxh = (h == 0) ? m.x : (h == 1) ? m.y : (h == 2) ? m.z : m.w;
  float smh = (h == 0) ? s.x : (h == 1) ? s.y : (h == 2) ? s.z : s.w;
  float rden = 1.f / (smh + SOFT_EPS);

  // pass 2: fp16 gather, 16 lanes/edge x half8, 4 edges/step, x2 unroll
  float acc[8];
#pragma unroll
  for (int j = 0; j < 8; ++j) acc[j] = 0.f;
  int base = rs;
  for (; base + 8 <= re; base += 8) {
    int e0 = base + quar, e1 = base + 4 + quar;
    int4 a0 = es[e0];
    int4 a1 = es[e1];
    float w0 = __expf(alpha_s[(size_t)e0 * 4 + h] - mxh);
    float w1 = __expf(alpha_s[(size_t)e1 * 4 + h] - mxh);
    half8 x0 = *(const half8*)(xwh + ((size_t)a0.z * N + a0.x) * 128 + cl * 8);
    half8 x1 = *(const half8*)(xwh + ((size_t)a1.z * N + a1.x) * 128 + cl * 8);
#pragma unroll
    for (int j = 0; j < 8; ++j) acc[j] += w0 * (float)x0[j] + w1 * (float)x1[j];
  }
  for (; base < re; base += 4) {
    int e = base + quar;
    if (e < re) {
      int4 a = es[e];
      float w = __expf(alpha_s[(size_t)e * 4 + h] - mxh);
      half8 xv = *(const half8*)(xwh + ((size_t)a.z * N + a.x) * 128 + cl * 8);
#pragma unroll
      for (int j = 0; j < 8; ++j) acc[j] += w * (float)xv[j];
    }
  }
  // merge the 4 quarters, then normalize
#pragma unroll
  for (int j = 0; j < 8; ++j) {
    acc[j] += __shfl_xor(acc[j], 16);
    acc[j] += __shfl_xor(acc[j], 32);
    acc[j] *= rden;
  }

  if (concat) {  // layer 1: relu(agg+b1) -> hbuf + fused bf16 split for layer-2 proj
    if (quar == 0) {
      float4 b0 = ((const float4*)bias)[cl * 2];
      float4 b1 = ((const float4*)bias)[cl * 2 + 1];
      float v[8] = {acc[0] + b0.x, acc[1] + b0.y, acc[2] + b0.z, acc[3] + b0.w,
                    acc[4] + b1.x, acc[5] + b1.y, acc[6] + b1.z, acc[7] + b1.w};
      u16x4 hv0, lv0, hv1, lv1;
#pragma unroll
      for (int j = 0; j < 8; ++j) {
        v[j] = v[j] > 0.f ? v[j] : 0.f;
        unsigned short hh, ll;
        bf16split(v[j], hh, ll);
        if (j < 4) { hv0[j] = hh; lv0[j] = ll; }
        else { hv1[j - 4] = hh; lv1[j - 4] = ll; }
      }
      float* orow = out + (size_t)d * 128 + cl * 8;
      *(float4*)orow = make_float4(v[0], v[1], v[2], v[3]);
      *(float4*)(orow + 4) = make_float4(v[4], v[5], v[6], v[7]);
      *(u16x4*)(xhi + (size_t)d * 128 + cl * 8) = hv0;
      *(u16x4*)(xhi + (size_t)d * 128 + cl * 8 + 4) = hv1;
      *(u16x4*)(xlo + (size_t)d * 128 + cl * 8) = lv0;
      *(u16x4*)(xlo + (size_t)d * 128 + cl * 8 + 4) = lv1;
    }
  } else {       // layer 2: mean over 4 heads + b3 -> out[d,32]
#pragma unroll
    for (int j = 0; j < 8; ++j) {
      acc[j] += __shfl_xor(acc[j], 4);
      acc[j] += __shfl_xor(acc[j], 8);
    }
    if (lane < 4) {
      float4 b0 = ((const float4*)bias)[cl * 2];
      float4 b1 = ((const float4*)bias)[cl * 2 + 1];
      float* orow = out + (size_t)d * 32 + cl * 8;
      *(float4*)orow = make_float4(0.25f * acc[0] + b0.x, 0.25f * acc[1] + b0.y,
                                   0.25f * acc[2] + b0.z, 0.25f * acc[3] + b0.w);
      *(float4*)(orow + 4) = make_float4(0.25f * acc[4] + b1.x, 0.25f * acc[5] + b1.y,
                                         0.25f * acc[6] + b1.z, 0.25f * acc[7] + b1.w);
    }
  }
}

extern "C" void kernel_launch(void* const* d_in, const int* in_sizes, int n_in,
                              void* d_out, int out_size, void* d_ws, size_t ws_size,
                              hipStream_t stream) {
  const float* x   = (const float*)d_in[0];
  const int*   ei  = (const int*)d_in[1];
  const float* ea  = (const float*)d_in[2];
  const int*   etp = (const int*)d_in[3];
  const float* w1  = (const float*)d_in[4];
  const float* q1  = (const float*)d_in[5];
  const float* k1  = (const float*)d_in[6];
  const float* e1  = (const float*)d_in[7];
  const float* le1 = (const float*)d_in[8];
  const float* b1  = (const float*)d_in[9];
  const float* w3  = (const float*)d_in[10];
  const float* q3  = (const float*)d_in[11];
  const float* k3  = (const float*)d_in[12];
  const float* e3  = (const float*)d_in[13];
  const float* le3 = (const float*)d_in[14];
  const float* b3  = (const float*)d_in[15];
  const int N = in_sizes[0] / 128;
  const int E = in_sizes[3];
  const int* srcp = ei;
  const int* dstp = ei + E;

  float* ws   = (float*)d_ws;
  _Float16* xwh = (_Float16*)ws;                     // 4*N*128 halfs
  float* qn   = ws + (size_t)2 * N * 128;            // 4*N*4 (after xwh: 4*N*128*2B = 2*N*128 floats)
  float* kn   = qn + (size_t)4 * N * 4;              // 4*N*4
  float* eks1 = kn + (size_t)4 * N * 4;              // E*4
  float* eks3 = eks1 + (size_t)E * 4;                // E*4
  float* alph = eks3 + (size_t)E * 4;                // E*4
  float* hbuf = alph + (size_t)E * 4;                // N*128
  float* leeb = hbuf + (size_t)N * 128;              // 128
  float* wqkb = leeb + 128;                          // 8192
  int* deg      = (int*)(wqkb + 8192);               // N
  int* rowst    = deg + N;                           // N+1
  int* cursor   = rowst + N + 1;                     // N
  int* bsum     = cursor + N;                        // 256
  int* boff     = bsum + 256;                        // 256
  uintptr_t pe = (uintptr_t)(boff + 256);
  pe = (pe + 15) & ~(uintptr_t)15;
  int4* es      = (int4*)pe;                         // E int4
  uintptr_t pa = (uintptr_t)(es + E);
  pa = (pa + 255) & ~(uintptr_t)255;
  unsigned short* xhi  = (unsigned short*)pa;        // N*128
  unsigned short* xlo  = xhi + (size_t)N * 128;      // N*128
  unsigned short* whiT = xlo + (size_t)N * 128;      // 4*128*128
  unsigned short* wloT = whiT + 4 * 128 * 128;       // 4*128*128
  (void)ws_size; (void)n_in; (void)out_size;

  int eb   = (E + 255) / 256;
  int nb4  = (N + 3) / 4;
  int nbs  = (N + 1023) / 1024;
  int pgy  = (N + 127) / 128;
  int qxb  = (N + 63) / 64;
  int cxb  = (N * 128 / 8 + 255) / 256;

  hipMemsetAsync(deg, 0, (size_t)N * sizeof(int), stream);
  hist_kernel<<<eb, 256, 0, stream>>>(dstp, deg, E);
  scanA_kernel<<<nbs, 256, 0, stream>>>(deg, bsum, N);
  scanB_kernel<<<1, 256, 0, stream>>>(bsum, boff, rowst, nbs, N);
  scanC_kernel<<<nbs, 256, 0, stream>>>(deg, boff, rowst, cursor, N);
  scatter_kernel<<<eb, 256, 0, stream>>>(srcp, dstp, etp, cursor, es, E);
  lee_kernel<<<1, 128, 0, stream>>>(le1, e1, le3, e3, leeb);
  ek2_kernel<<<eb, 256, 0, stream>>>(es, ea, leeb, eks1, eks3, E);
  wqk_kernel<<<32, 256, 0, stream>>>(w1, q1, k1, w3, q3, k3, wqkb);
  convx_kernel<<<cxb, 256, 0, stream>>>(x, xhi, xlo, N * 128 / 8);

  for (int layer = 0; layer < 2; ++layer) {
    const float* xin = layer ? hbuf : x;
    const float* w   = layer ? w3 : w1;
    const float* eks = layer ? eks3 : eks1;
    const float* bias = layer ? b3 : b1;
    float* outp = layer ? (float*)d_out : hbuf;

    convw_kernel<<<dim3(128, 4), 128, 0, stream>>>(w, whiT, wloT);
    proj_mfma_kernel<<<dim3(4, pgy), 256, 0, stream>>>(xhi, xlo, whiT, wloT, xwh, N);
    qkx_kernel<<<qxb, 256, 0, stream>>>(xin, wqkb + layer * 4096, qn, kn, N);
    agg_kernel<<<nb4, 256, 0, stream>>>(es, rowst, qn, kn, eks, alph, xwh,
                                        bias, outp, xhi, xlo, N, layer == 0 ? 1 : 0);
  }
}

// Round 11
// 501.945 us; speedup vs baseline: 1.4919x; 1.0134x over previous
//
#include <hip/hip_runtime.h>

// RGATNetwork: 2x RGATConv (R=4, H=4, C=32, HC=128, F_E=16) on N=50k nodes, E=800k edges.
// R11: agg de-VALU-ified. R10 was VALU-bound (80%): online-softmax butterfly did
// ~48 expf/node and pass 2 recomputed exp per edge. Now: sweep A = alpha + plain
// max (no exp); deg<=64 fast path reuses register alpha for the exp+sum sweep
// (4 expf/lane/node total); pass 2 loads precomputed w (no exp) and accumulates
// via fmaf((float)h, w, acc) to get v_fma_mix. Rest identical to R10.

#define NEG_SLOPE 0.2f
#define SOFT_EPS 1e-16f

typedef __attribute__((ext_vector_type(8))) short bf16x8;
typedef __attribute__((ext_vector_type(4))) float f32x4;
typedef __attribute__((ext_vector_type(4))) unsigned short u16x4;
typedef __attribute__((ext_vector_type(4))) _Float16 half4;
typedef __attribute__((ext_vector_type(8))) _Float16 half8;

__device__ __forceinline__ void bf16split(float f, unsigned short& h, unsigned short& l) {
  unsigned u = __float_as_uint(f);
  unsigned r = u + 0x7FFFu + ((u >> 16) & 1u);
  h = (unsigned short)(r >> 16);
  float fh = __uint_as_float(((unsigned)h) << 16);
  float d = f - fh;
  unsigned u2 = __float_as_uint(d);
  unsigned r2 = u2 + 0x7FFFu + ((u2 >> 16) & 1u);
  l = (unsigned short)(r2 >> 16);
}

// lee[f,h]: t<64 layer1, t>=64 layer3
__global__ void lee_kernel(const float* __restrict__ le1, const float* __restrict__ e1,
                           const float* __restrict__ le3, const float* __restrict__ e3,
                           float* __restrict__ lee) {
  int t = threadIdx.x;
  const float* le = (t < 64) ? le1 : le3;
  const float* ee = (t < 64) ? e1 : e3;
  int u = t & 63, f = u >> 2, h = u & 3;
  float acc = 0.f;
  for (int o = 0; o < 128; ++o) acc += le[f * 128 + o] * ee[o * 4 + h];
  lee[t] = acc;
}

// wqk[L][r][f][j] = sum_o w[r,f,o] * {q|k}[o, j&3]
__global__ __launch_bounds__(256) void wqk_kernel(
    const float* __restrict__ w1, const float* __restrict__ q1, const float* __restrict__ k1,
    const float* __restrict__ w3, const float* __restrict__ q3, const float* __restrict__ k3,
    float* __restrict__ wqk) {
  int idx = blockIdx.x * 256 + threadIdx.x;
  int L = idx >> 12, rem = idx & 4095;
  int r = rem >> 10, rem2 = rem & 1023, f = rem2 >> 3, j = rem2 & 7;
  const float* w = L ? w3 : w1;
  const float* qk = (j < 4) ? (L ? q3 : q1) : (L ? k3 : k1);
  int h = j & 3;
  const float* wrow = w + ((size_t)r * 128 + f) * 128;
  float acc = 0.f;
  for (int o = 0; o < 128; ++o) acc += wrow[o] * qk[o * 4 + h];
  wqk[idx] = acc;
}

// ---- CSR build ----
__global__ __launch_bounds__(256) void hist_kernel(const int* __restrict__ dst,
                                                   int* __restrict__ deg, int E) {
  int e = blockIdx.x * 256 + threadIdx.x;
  if (e < E) atomicAdd(&deg[dst[e]], 1);
}

__global__ __launch_bounds__(256) void scanA_kernel(const int* __restrict__ deg,
                                                    int* __restrict__ bsum, int N) {
  int b = blockIdx.x, t = threadIdx.x;
  int base = b * 1024 + t * 4;
  int s = 0;
#pragma unroll
  for (int j = 0; j < 4; ++j) {
    int i = base + j;
    if (i < N) s += deg[i];
  }
#pragma unroll
  for (int o = 1; o < 64; o <<= 1) s += __shfl_xor(s, o);
  __shared__ int wsum[4];
  if ((t & 63) == 0) wsum[t >> 6] = s;
  __syncthreads();
  if (t == 0) bsum[b] = wsum[0] + wsum[1] + wsum[2] + wsum[3];
}

__global__ __launch_bounds__(256) void scanB_kernel(const int* __restrict__ bsum,
                                                    int* __restrict__ boff,
                                                    int* __restrict__ row_start,
                                                    int nb, int N) {
  int t = threadIdx.x;
  int v = (t < nb) ? bsum[t] : 0;
  int inc = v;
#pragma unroll
  for (int o = 1; o < 64; o <<= 1) {
    int u = __shfl_up(inc, o);
    if ((t & 63) >= o) inc += u;
  }
  __shared__ int wt[4];
  if ((t & 63) == 63) wt[t >> 6] = inc;
  __syncthreads();
  int add = 0;
  for (int wv = 0; wv < (t >> 6); ++wv) add += wt[wv];
  inc += add;
  if (t < nb) boff[t] = inc - v;
  if (t == 255) row_start[N] = inc;
}

__global__ __launch_bounds__(256) void scanC_kernel(const int* __restrict__ deg,
                                                    const int* __restrict__ boff,
                                                    int* __restrict__ row_start,
                                                    int* __restrict__ cursor, int N) {
  int b = blockIdx.x, t = threadIdx.x;
  int base = b * 1024 + t * 4;
  int d[4];
  int s = 0;
#pragma unroll
  for (int j = 0; j < 4; ++j) {
    int i = base + j;
    d[j] = (i < N) ? deg[i] : 0;
    s += d[j];
  }
  int inc = s;
#pragma unroll
  for (int o = 1; o < 64; o <<= 1) {
    int u = __shfl_up(inc, o);
    if ((t & 63) >= o) inc += u;
  }
  __shared__ int wt[4];
  if ((t & 63) == 63) wt[t >> 6] = inc;
  __syncthreads();
  int add = boff[b];
  for (int wv = 0; wv < (t >> 6); ++wv) add += wt[wv];
  int off = add + inc - s;
#pragma unroll
  for (int j = 0; j < 4; ++j) {
    int i = base + j;
    if (i < N) {
      row_start[i] = off;
      cursor[i] = off;
      off += d[j];
    }
  }
}

// packed scatter: es[pos] = {src, dst, et, eid}
__global__ __launch_bounds__(256) void scatter_kernel(
    const int* __restrict__ src, const int* __restrict__ dst, const int* __restrict__ et,
    int* __restrict__ cursor, int4* __restrict__ es, int E) {
  int e = blockIdx.x * 256 + threadIdx.x;
  if (e >= E) return;
  int d = dst[e];
  int pos = atomicAdd(&cursor[d], 1);
  es[pos] = make_int4(src[e], d, et[e], e);
}

// ek for BOTH layers at dst-sorted position i
__global__ __launch_bounds__(256) void ek2_kernel(
    const int4* __restrict__ es, const float* __restrict__ ea,
    const float* __restrict__ lee, float* __restrict__ eks1,
    float* __restrict__ eks3, int E) {
  __shared__ float sl[128];
  if (threadIdx.x < 128) sl[threadIdx.x] = lee[threadIdx.x];
  __syncthreads();
  int i = blockIdx.x * 256 + threadIdx.x;
  if (i >= E) return;
  int eid = es[i].w;
  const float4* a4 = (const float4*)(ea + (size_t)eid * 16);
  float a1[4] = {0, 0, 0, 0}, a3[4] = {0, 0, 0, 0};
#pragma unroll
  for (int ii = 0; ii < 4; ++ii) {
    float4 v = a4[ii];
    int f = ii * 4;
#pragma unroll
    for (int h = 0; h < 4; ++h) {
      a1[h] += v.x * sl[f * 4 + h] + v.y * sl[(f + 1) * 4 + h] +
               v.z * sl[(f + 2) * 4 + h] + v.w * sl[(f + 3) * 4 + h];
      a3[h] += v.x * sl[64 + f * 4 + h] + v.y * sl[64 + (f + 1) * 4 + h] +
               v.z * sl[64 + (f + 2) * 4 + h] + v.w * sl[64 + (f + 3) * 4 + h];
    }
  }
  *(float4*)(eks1 + (size_t)i * 4) = make_float4(a1[0], a1[1], a1[2], a1[3]);
  *(float4*)(eks3 + (size_t)i * 4) = make_float4(a3[0], a3[1], a3[2], a3[3]);
}

// ---- bf16 split conversion (layer-1 x only) ----
__global__ __launch_bounds__(256) void convx_kernel(const float* __restrict__ in,
                                                    unsigned short* __restrict__ hi,
                                                    unsigned short* __restrict__ lo,
                                                    int total8) {
  int i = blockIdx.x * 256 + threadIdx.x;
  if (i >= total8) return;
  const float4* p = (const float4*)in + (size_t)i * 2;
  float4 a = p[0], b = p[1];
  float v[8] = {a.x, a.y, a.z, a.w, b.x, b.y, b.z, b.w};
  bf16x8 hv, lv;
#pragma unroll
  for (int j = 0; j < 8; ++j) {
    unsigned short h, l;
    bf16split(v[j], h, l);
    hv[j] = (short)h; lv[j] = (short)l;
  }
  *(bf16x8*)(hi + (size_t)i * 8) = hv;
  *(bf16x8*)(lo + (size_t)i * 8) = lv;
}

__global__ void convw_kernel(const float* __restrict__ w,
                             unsigned short* __restrict__ hiT,
                             unsigned short* __restrict__ loT) {
  int f = blockIdx.x, r = blockIdx.y, o = threadIdx.x;
  float v = w[((size_t)r * 128 + f) * 128 + o];
  unsigned short h, l;
  bf16split(v, h, l);
  hiT[((size_t)r * 128 + o) * 128 + f] = h;
  loT[((size_t)r * 128 + o) * 128 + f] = l;
}

// ---- proj via MFMA, w staged in LDS fragment-major; fp16 output ----
__global__ __launch_bounds__(256) void proj_mfma_kernel(
    const unsigned short* __restrict__ xhi, const unsigned short* __restrict__ xlo,
    const unsigned short* __restrict__ whiT, const unsigned short* __restrict__ wloT,
    _Float16* __restrict__ xwh, int N) {
  __shared__ bf16x8 wl_h[2048];  // 32 KB
  __shared__ bf16x8 wl_l[2048];  // 32 KB
  int r = blockIdx.x;
  int nb = blockIdx.y * 128;
  int t = threadIdx.x;
  const unsigned short* wh = whiT + (size_t)r * (128 * 128);
  const unsigned short* wl = wloT + (size_t)r * (128 * 128);

#pragma unroll
  for (int j = 0; j < 8; ++j) {
    int i = j * 256 + t;
    int c = i & 15, q = (i >> 4) & 3, kc = (i >> 6) & 3, ot = i >> 8;
    int srco = (ot * 16 + c) * 128 + kc * 32 + q * 8;
    wl_h[i] = *(const bf16x8*)(wh + srco);
    wl_l[i] = *(const bf16x8*)(wl + srco);
  }
  __syncthreads();

  int wv = t >> 6;
  int lane = t & 63;
  int c = lane & 15, q = lane >> 4;
  int nodebase = nb + wv * 32;
  int n0 = nodebase + c;
  int n1 = nodebase + 16 + c;
  int n0c = n0 < N ? n0 : N - 1;
  int n1c = n1 < N ? n1 : N - 1;

  f32x4 acc[8][2];
#pragma unroll
  for (int ot = 0; ot < 8; ++ot)
#pragma unroll
    for (int nt = 0; nt < 2; ++nt) acc[ot][nt] = (f32x4){0.f, 0.f, 0.f, 0.f};

  bf16x8 xb[2][4];
  {
    int k0 = q * 8;
    xb[0][0] = *(const bf16x8*)(xhi + (size_t)n0c * 128 + k0);
    xb[0][1] = *(const bf16x8*)(xlo + (size_t)n0c * 128 + k0);
    xb[0][2] = *(const bf16x8*)(xhi + (size_t)n1c * 128 + k0);
    xb[0][3] = *(const bf16x8*)(xlo + (size_t)n1c * 128 + k0);
  }
#pragma unroll
  for (int kc = 0; kc < 4; ++kc) {
    if (kc < 3) {
      int k0 = (kc + 1) * 32 + q * 8;
      xb[(kc + 1) & 1][0] = *(const bf16x8*)(xhi + (size_t)n0c * 128 + k0);
      xb[(kc + 1) & 1][1] = *(const bf16x8*)(xlo + (size_t)n0c * 128 + k0);
      xb[(kc + 1) & 1][2] = *(const bf16x8*)(xhi + (size_t)n1c * 128 + k0);
      xb[(kc + 1) & 1][3] = *(const bf16x8*)(xlo + (size_t)n1c * 128 + k0);
    }
    bf16x8 b0h = xb[kc & 1][0], b0l = xb[kc & 1][1];
    bf16x8 b1h = xb[kc & 1][2], b1l = xb[kc & 1][3];
#pragma unroll
    for (int ot = 0; ot < 8; ++ot) {
      int fi = ((ot * 4 + kc) * 4 + q) * 16 + c;
      bf16x8 ah = wl_h[fi];
      bf16x8 al = wl_l[fi];
      acc[ot][0] = __builtin_amdgcn_mfma_f32_16x16x32_bf16(ah, b0h, acc[ot][0], 0, 0, 0);
      acc[ot][0] = __builtin_amdgcn_mfma_f32_16x16x32_bf16(ah, b0l, acc[ot][0], 0, 0, 0);
      acc[ot][0] = __builtin_amdgcn_mfma_f32_16x16x32_bf16(al, b0h, acc[ot][0], 0, 0, 0);
      acc[ot][1] = __builtin_amdgcn_mfma_f32_16x16x32_bf16(ah, b1h, acc[ot][1], 0, 0, 0);
      acc[ot][1] = __builtin_amdgcn_mfma_f32_16x16x32_bf16(ah, b1l, acc[ot][1], 0, 0, 0);
      acc[ot][1] = __builtin_amdgcn_mfma_f32_16x16x32_bf16(al, b1h, acc[ot][1], 0, 0, 0);
    }
  }

#pragma unroll
  for (int nt = 0; nt < 2; ++nt) {
    int n = nodebase + nt * 16 + c;
    if (n < N) {
      _Float16* basep = xwh + ((size_t)r * N + n) * 128 + q * 4;
#pragma unroll
      for (int ot = 0; ot < 8; ++ot) {
        f32x4 a = acc[ot][nt];
        half4 hv;
        hv[0] = (_Float16)a.x; hv[1] = (_Float16)a.y;
        hv[2] = (_Float16)a.z; hv[3] = (_Float16)a.w;
        *(half4*)(basep + ot * 16) = hv;
      }
    }
  }
}

// qn/kn from x via folded wqk
__global__ __launch_bounds__(256) void qkx_kernel(
    const float* __restrict__ xin, const float* __restrict__ wqk,
    float* __restrict__ qn, float* __restrict__ kn, int N) {
  __shared__ float sx[64 * 132];
  __shared__ float swqk[4 * 1032];
  int nb = blockIdx.x * 64;
  int t = threadIdx.x;
#pragma unroll
  for (int j = 0; j < 16; ++j) {
    int i = j * 256 + t;
    swqk[(i >> 10) * 1032 + (i & 1023)] = wqk[i];
  }
#pragma unroll
  for (int j = 0; j < 8; ++j) {
    int i = j * 256 + t;
    int n = nb + (i >> 5); if (n >= N) n = N - 1;
    ((float4*)sx)[(i >> 5) * 33 + (i & 31)] =
        ((const float4*)(xin + (size_t)n * 128))[i & 31];
  }
  __syncthreads();
  int rl = t >> 2, r = t & 3;
  float aq0 = 0, aq1 = 0, aq2 = 0, aq3 = 0;
  float ak0 = 0, ak1 = 0, ak2 = 0, ak3 = 0;
  const float* xr = sx + rl * 132;
  const float* wb = swqk + r * 1032;
  for (int f = 0; f < 128; ++f) {
    float xv = xr[f];
    float4 qw = *(const float4*)(wb + f * 8);
    float4 kw = *(const float4*)(wb + f * 8 + 4);
    aq0 += xv * qw.x; aq1 += xv * qw.y; aq2 += xv * qw.z; aq3 += xv * qw.w;
    ak0 += xv * kw.x; ak1 += xv * kw.y; ak2 += xv * kw.z; ak3 += xv * kw.w;
  }
  int n = nb + rl;
  if (n < N) {
    *(float4*)(qn + ((size_t)r * N + n) * 4) = make_float4(aq0, aq1, aq2, aq3);
    *(float4*)(kn + ((size_t)r * N + n) * 4) = make_float4(ak0, ak1, ak2, ak3);
  }
}

// fused alpha + softmax + fp16 gather-aggregate + epilogue. One wave per dst.
// Sweep A: alpha + plain max. deg<=64 fast path: exp from registers.
// Pass 2: precomputed w, no exp, v_fma_mix accumulation.
__global__ __launch_bounds__(256) void agg_kernel(
    const int4* __restrict__ es, const int* __restrict__ row_start,
    const float* __restrict__ qn, const float* __restrict__ kn,
    const float* __restrict__ eks, float* __restrict__ alpha_s,
    const _Float16* __restrict__ xwh, const float* __restrict__ bias,
    float* __restrict__ out, unsigned short* __restrict__ xhi,
    unsigned short* __restrict__ xlo, int N, int concat) {
  int d = blockIdx.x * 4 + (threadIdx.x >> 6);
  if (d >= N) return;
  int lane = threadIdx.x & 63;
  int rs = row_start[d], re = row_start[d + 1];
  int deg = re - rs;

  float4 qv0 = *(const float4*)(qn + (size_t)d * 4);
  float4 qv1 = *(const float4*)(qn + ((size_t)N + d) * 4);
  float4 qv2 = *(const float4*)(qn + ((size_t)2 * N + d) * 4);
  float4 qv3 = *(const float4*)(qn + ((size_t)3 * N + d) * 4);

  // sweep A: alpha -> alpha_s; plain per-head max (no exp)
  float4 m = make_float4(-1e30f, -1e30f, -1e30f, -1e30f);
  float4 a_last = m;
  for (int i = rs + lane; i < re; i += 64) {
    int4 v = es[i];
    float4 kv = *(const float4*)(kn + ((size_t)v.z * N + v.x) * 4);
    float4 ev = *(const float4*)(eks + (size_t)i * 4);
    float4 q4 = (v.z == 0) ? qv0 : (v.z == 1) ? qv1 : (v.z == 2) ? qv2 : qv3;
    float4 a = make_float4(q4.x + kv.x + ev.x, q4.y + kv.y + ev.y,
                           q4.z + kv.z + ev.z, q4.w + kv.w + ev.w);
    a.x = a.x > 0.f ? a.x : NEG_SLOPE * a.x;
    a.y = a.y > 0.f ? a.y : NEG_SLOPE * a.y;
    a.z = a.z > 0.f ? a.z : NEG_SLOPE * a.z;
    a.w = a.w > 0.f ? a.w : NEG_SLOPE * a.w;
    if (deg > 64) ((float4*)alpha_s)[i] = a;  // small-deg path never re-reads
    m.x = fmaxf(m.x, a.x); m.y = fmaxf(m.y, a.y);
    m.z = fmaxf(m.z, a.z); m.w = fmaxf(m.w, a.w);
    a_last = a;
  }
#pragma unroll
  for (int o = 32; o >= 1; o >>= 1) {
    m.x = fmaxf(m.x, __shfl_xor(m.x, o));
    m.y = fmaxf(m.y, __shfl_xor(m.y, o));
    m.z = fmaxf(m.z, __shfl_xor(m.z, o));
    m.w = fmaxf(m.w, __shfl_xor(m.w, o));
  }
  // sweep B: exp + sum; write w = exp(a-m) into alpha_s
  float4 s = make_float4(0.f, 0.f, 0.f, 0.f);
  if (deg <= 64) {
    if (lane < deg) {
      float4 e4 = make_float4(__expf(a_last.x - m.x), __expf(a_last.y - m.y),
                              __expf(a_last.z - m.z), __expf(a_last.w - m.w));
      ((float4*)alpha_s)[rs + lane] = e4;
      s = e4;
    }
  } else {
    for (int i = rs + lane; i < re; i += 64) {
      float4 a = ((const float4*)alpha_s)[i];
      float4 e4 = make_float4(__expf(a.x - m.x), __expf(a.y - m.y),
                              __expf(a.z - m.z), __expf(a.w - m.w));
      ((float4*)alpha_s)[i] = e4;
      s.x += e4.x; s.y += e4.y; s.z += e4.z; s.w += e4.w;
    }
  }
#pragma unroll
  for (int o = 32; o >= 1; o >>= 1) {
    s.x += __shfl_xor(s.x, o); s.y += __shfl_xor(s.y, o);
    s.z += __shfl_xor(s.z, o); s.w += __shfl_xor(s.w, o);
  }

  int quar = lane >> 4;  // which edge of the group of 4
  int cl = lane & 15;    // 8-channel group within the 128-wide row
  int h = cl >> 2;       // head
  float smh = (h == 0) ? s.x : (h == 1) ? s.y : (h == 2) ? s.z : s.w;
  float rden = 1.f / (smh + SOFT_EPS);

  // pass 2: fp16 gather, 16 lanes/edge x half8, 8 edges/iter, no exp
  float acc[8];
#pragma unroll
  for (int j = 0; j < 8; ++j) acc[j] = 0.f;
  int base = rs;
  for (; base + 8 <= re; base += 8) {
    int e0 = base + quar, e1 = base + 4 + quar;
    int4 a0 = es[e0];
    int4 a1 = es[e1];
    float w0 = alpha_s[(size_t)e0 * 4 + h];
    float w1 = alpha_s[(size_t)e1 * 4 + h];
    half8 x0 = *(const half8*)(xwh + ((size_t)a0.z * N + a0.x) * 128 + cl * 8);
    half8 x1 = *(const half8*)(xwh + ((size_t)a1.z * N + a1.x) * 128 + cl * 8);
#pragma unroll
    for (int j = 0; j < 8; ++j) {
      acc[j] = fmaf((float)x0[j], w0, acc[j]);
      acc[j] = fmaf((float)x1[j], w1, acc[j]);
    }
  }
  for (; base < re; base += 4) {
    int e = base + quar;
    if (e < re) {
      int4 a = es[e];
      float w = alpha_s[(size_t)e * 4 + h];
      half8 xv = *(const half8*)(xwh + ((size_t)a.z * N + a.x) * 128 + cl * 8);
#pragma unroll
      for (int j = 0; j < 8; ++j) acc[j] = fmaf((float)xv[j], w, acc[j]);
    }
  }
  // merge the 4 quarters, then normalize
#pragma unroll
  for (int j = 0; j < 8; ++j) {
    acc[j] += __shfl_xor(acc[j], 16);
    acc[j] += __shfl_xor(acc[j], 32);
    acc[j] *= rden;
  }

  if (concat) {  // layer 1: relu(agg+b1) -> hbuf + fused bf16 split for layer-2 proj
    if (quar == 0) {
      float4 b0 = ((const float4*)bias)[cl * 2];
      float4 b1 = ((const float4*)bias)[cl * 2 + 1];
      float v[8] = {acc[0] + b0.x, acc[1] + b0.y, acc[2] + b0.z, acc[3] + b0.w,
                    acc[4] + b1.x, acc[5] + b1.y, acc[6] + b1.z, acc[7] + b1.w};
      u16x4 hv0, lv0, hv1, lv1;
#pragma unroll
      for (int j = 0; j < 8; ++j) {
        v[j] = v[j] > 0.f ? v[j] : 0.f;
        unsigned short hh, ll;
        bf16split(v[j], hh, ll);
        if (j < 4) { hv0[j] = hh; lv0[j] = ll; }
        else { hv1[j - 4] = hh; lv1[j - 4] = ll; }
      }
      float* orow = out + (size_t)d * 128 + cl * 8;
      *(float4*)orow = make_float4(v[0], v[1], v[2], v[3]);
      *(float4*)(orow + 4) = make_float4(v[4], v[5], v[6], v[7]);
      *(u16x4*)(xhi + (size_t)d * 128 + cl * 8) = hv0;
      *(u16x4*)(xhi + (size_t)d * 128 + cl * 8 + 4) = hv1;
      *(u16x4*)(xlo + (size_t)d * 128 + cl * 8) = lv0;
      *(u16x4*)(xlo + (size_t)d * 128 + cl * 8 + 4) = lv1;
    }
  } else {       // layer 2: mean over 4 heads + b3 -> out[d,32]
#pragma unroll
    for (int j = 0; j < 8; ++j) {
      acc[j] += __shfl_xor(acc[j], 4);
      acc[j] += __shfl_xor(acc[j], 8);
    }
    if (lane < 4) {
      float4 b0 = ((const float4*)bias)[cl * 2];
      float4 b1 = ((const float4*)bias)[cl * 2 + 1];
      float* orow = out + (size_t)d * 32 + cl * 8;
      *(float4*)orow = make_float4(0.25f * acc[0] + b0.x, 0.25f * acc[1] + b0.y,
                                   0.25f * acc[2] + b0.z, 0.25f * acc[3] + b0.w);
      *(float4*)(orow + 4) = make_float4(0.25f * acc[4] + b1.x, 0.25f * acc[5] + b1.y,
                                         0.25f * acc[6] + b1.z, 0.25f * acc[7] + b1.w);
    }
  }
}

extern "C" void kernel_launch(void* const* d_in, const int* in_sizes, int n_in,
                              void* d_out, int out_size, void* d_ws, size_t ws_size,
                              hipStream_t stream) {
  const float* x   = (const float*)d_in[0];
  const int*   ei  = (const int*)d_in[1];
  const float* ea  = (const float*)d_in[2];
  const int*   etp = (const int*)d_in[3];
  const float* w1  = (const float*)d_in[4];
  const float* q1  = (const float*)d_in[5];
  const float* k1  = (const float*)d_in[6];
  const float* e1  = (const float*)d_in[7];
  const float* le1 = (const float*)d_in[8];
  const float* b1  = (const float*)d_in[9];
  const float* w3  = (const float*)d_in[10];
  const float* q3  = (const float*)d_in[11];
  const float* k3  = (const float*)d_in[12];
  const float* e3  = (const float*)d_in[13];
  const float* le3 = (const float*)d_in[14];
  const float* b3  = (const float*)d_in[15];
  const int N = in_sizes[0] / 128;
  const int E = in_sizes[3];
  const int* srcp = ei;
  const int* dstp = ei + E;

  float* ws   = (float*)d_ws;
  _Float16* xwh = (_Float16*)ws;                     // 4*N*128 halfs
  float* qn   = ws + (size_t)2 * N * 128;            // 4*N*4
  float* kn   = qn + (size_t)4 * N * 4;              // 4*N*4
  float* eks1 = kn + (size_t)4 * N * 4;              // E*4
  float* eks3 = eks1 + (size_t)E * 4;                // E*4
  float* alph = eks3 + (size_t)E * 4;                // E*4
  float* hbuf = alph + (size_t)E * 4;                // N*128
  float* leeb = hbuf + (size_t)N * 128;              // 128
  float* wqkb = leeb + 128;                          // 8192
  int* deg      = (int*)(wqkb + 8192);               // N
  int* rowst    = deg + N;                           // N+1
  int* cursor   = rowst + N + 1;                     // N
  int* bsum     = cursor + N;                        // 256
  int* boff     = bsum + 256;                        // 256
  uintptr_t pe = (uintptr_t)(boff + 256);
  pe = (pe + 15) & ~(uintptr_t)15;
  int4* es      = (int4*)pe;                         // E int4
  uintptr_t pa = (uintptr_t)(es + E);
  pa = (pa + 255) & ~(uintptr_t)255;
  unsigned short* xhi  = (unsigned short*)pa;        // N*128
  unsigned short* xlo  = xhi + (size_t)N * 128;      // N*128
  unsigned short* whiT = xlo + (size_t)N * 128;      // 4*128*128
  unsigned short* wloT = whiT + 4 * 128 * 128;       // 4*128*128
  (void)ws_size; (void)n_in; (void)out_size;

  int eb   = (E + 255) / 256;
  int nb4  = (N + 3) / 4;
  int nbs  = (N + 1023) / 1024;
  int pgy  = (N + 127) / 128;
  int qxb  = (N + 63) / 64;
  int cxb  = (N * 128 / 8 + 255) / 256;

  hipMemsetAsync(deg, 0, (size_t)N * sizeof(int), stream);
  hist_kernel<<<eb, 256, 0, stream>>>(dstp, deg, E);
  scanA_kernel<<<nbs, 256, 0, stream>>>(deg, bsum, N);
  scanB_kernel<<<1, 256, 0, stream>>>(bsum, boff, rowst, nbs, N);
  scanC_kernel<<<nbs, 256, 0, stream>>>(deg, boff, rowst, cursor, N);
  scatter_kernel<<<eb, 256, 0, stream>>>(srcp, dstp, etp, cursor, es, E);
  lee_kernel<<<1, 128, 0, stream>>>(le1, e1, le3, e3, leeb);
  ek2_kernel<<<eb, 256, 0, stream>>>(es, ea, leeb, eks1, eks3, E);
  wqk_kernel<<<32, 256, 0, stream>>>(w1, q1, k1, w3, q3, k3, wqkb);
  convx_kernel<<<cxb, 256, 0, stream>>>(x, xhi, xlo, N * 128 / 8);

  for (int layer = 0; layer < 2; ++layer) {
    const float* xin = layer ? hbuf : x;
    const float* w   = layer ? w3 : w1;
    const float* eks = layer ? eks3 : eks1;
    const float* bias = layer ? b3 : b1;
    float* outp = layer ? (float*)d_out : hbuf;

    convw_kernel<<<dim3(128, 4), 128, 0, stream>>>(w, whiT, wloT);
    proj_mfma_kernel<<<dim3(4, pgy), 256, 0, stream>>>(xhi, xlo, whiT, wloT, xwh, N);
    qkx_kernel<<<qxb, 256, 0, stream>>>(xin, wqkb + layer * 4096, qn, kn, N);
    agg_kernel<<<nb4, 256, 0, stream>>>(es, rowst, qn, kn, eks, alph, xwh,
                                        bias, outp, xhi, xlo, N, layer == 0 ? 1 : 0);
  }
}